// Round 1
// baseline (1560.624 us; speedup 1.0000x reference)
//
#include <hip/hip_runtime.h>
#include <cmath>
#include <cstdint>

// Problem constants (B=8, N=4096, C=1024, H=16, D=64, FF=4096)
#define MTOK 32768   // B*N tokens
#define CDIM 1024
#define SEQ  4096
#define NHEAD 16
#define HDIM 64
#define FFDIM 4096

typedef __attribute__((ext_vector_type(8))) short short8;   // 8 bf16 (4 VGPRs)
typedef __attribute__((ext_vector_type(4))) float f32x4;

static __device__ __forceinline__ float b2f(unsigned short u){
  union { unsigned int i; float f; } c; c.i = ((unsigned int)u)<<16; return c.f;
}
static __device__ __forceinline__ unsigned short f2b(float f){
  union { float f; unsigned int i; } c; c.f = f;
  return (unsigned short)((c.i + 0x7fffu + ((c.i>>16)&1u)) >> 16);  // RNE
}
// async global->LDS, 16B/lane; LDS dest = wave-uniform base + lane*16
static __device__ __forceinline__ void async16(const void* g, void* l){
  __builtin_amdgcn_global_load_lds((const __attribute__((address_space(1))) void*)g,
                                   (__attribute__((address_space(3))) void*)l, 16, 0, 0);
}

// ---------------- mask dtype detection + decode ----------------
__global__ void detect_mask_kernel(const unsigned int* __restrict__ m, int* __restrict__ flag){
  __shared__ int any;
  if(threadIdx.x==0) any=0;
  __syncthreads();
  int loc=0;
  for(int i=threadIdx.x;i<8192;i+=256) if(m[i]>1u) loc=1;
  if(loc) atomicOr(&any,1);
  __syncthreads();
  if(threadIdx.x==0) *flag=any;
}
__global__ void decode_mask_kernel(const void* __restrict__ m, const int* __restrict__ flag,
                                   float* __restrict__ validf){
  int i = blockIdx.x*256 + threadIdx.x;   // grid covers MTOK exactly
  int pad = (*flag) ? (int)((const unsigned char*)m)[i] : ((const int*)m)[i];
  validf[i] = pad ? 0.f : 1.f;
}

// ---------------- fp32 -> bf16 cast (weights) ----------------
__global__ void cast_bf16_kernel(const float* __restrict__ x, unsigned short* __restrict__ y, int n){
  int i = (blockIdx.x*256 + threadIdx.x)*4;
  if(i>=n) return;
  float4 v = *(const float4*)(x+i);
  ushort4 o; o.x=f2b(v.x); o.y=f2b(v.y); o.z=f2b(v.z); o.w=f2b(v.w);
  *(ushort4*)(y+i)=o;
}

// ---------------- LayerNorm (C=1024) -> bf16 ----------------
__global__ __launch_bounds__(256) void ln_kernel(const float* __restrict__ x,
    const float* __restrict__ g, const float* __restrict__ bt, unsigned short* __restrict__ out){
  int row = blockIdx.x, t = threadIdx.x;
  const float* xr = x + (size_t)row*CDIM;
  float4 v = *(const float4*)(xr + t*4);
  float s1 = v.x+v.y+v.z+v.w;
  float s2 = v.x*v.x+v.y*v.y+v.z*v.z+v.w*v.w;
  #pragma unroll
  for(int off=32; off>0; off>>=1){ s1+=__shfl_down(s1,off); s2+=__shfl_down(s2,off); }
  __shared__ float a1[4], a2[4];
  __shared__ float mu_s, rs_s;
  if((t&63)==0){ a1[t>>6]=s1; a2[t>>6]=s2; }
  __syncthreads();
  if(t==0){
    float u1=a1[0]+a1[1]+a1[2]+a1[3], u2=a2[0]+a2[1]+a2[2]+a2[3];
    float mu=u1*(1.f/CDIM);
    mu_s=mu; rs_s=rsqrtf(u2*(1.f/CDIM)-mu*mu+1e-5f);
  }
  __syncthreads();
  float mu=mu_s, rs=rs_s;
  float4 gg=*(const float4*)(g+t*4), bb=*(const float4*)(bt+t*4);
  ushort4 o;
  o.x=f2b((v.x-mu)*rs*gg.x+bb.x);
  o.y=f2b((v.y-mu)*rs*gg.y+bb.y);
  o.z=f2b((v.z-mu)*rs*gg.z+bb.z);
  o.w=f2b((v.w-mu)*rs*gg.w+bb.w);
  *(ushort4*)(out+(size_t)row*CDIM+t*4)=o;
}

// ---------------- GEMM: C[M,N] = A[M,K] * Bw[N,K]^T, bf16 in, fused epilogue ----
// 256x256 tile, BK=64, 512 threads (8 waves, 2x4), 8-phase schedule with counted
// vmcnt (T3+T4), XOR-chunk LDS swizzle (T2, pre-swizzled global src + swizzled
// ds_read, SQ_LDS_BANK_CONFLICT==0 on this pattern), setprio around MFMA (T5).
// Per wave: 128x64 output as 2x2 quadrants of 64x32. A-frags cached across nq
// phases, B-frags cached across mq phases (24 ds_read_b128 / K-tile).
// Staging: one half-tile (128x64) per phase, placed one phase after that
// half's last LDS read:
//   phase0: Ah1(t+1)->buf^1   (old Ah1 last read t-1/ph2)
//   phase1: Bh1(t+1)->buf^1   (old Bh1 last read t-1/ph1)
//   phase2: Ah0(t+2)->buf     (Ah0 last read ph0)
//   phase3: Bh0(t+2)->buf     (Bh0 last read ph0; via reg-cache ph2 uses regs)
// Boundary: single s_waitcnt vmcnt(4) per K-tile (2 half-tiles stay in flight).
// XCD-aware bijective block remap (total blocks % 8 == 0 for all launches).
// MODE 0: QKV  -> Cb[m,3072] = phi/mask per column third (extra=validf, bias=qkv_b)
// MODE 1: XRES -> Cf[m,N] = acc + bias + extra[m,N]   (out-proj + residual, Cf=d_out)
// MODE 2: GELU -> Cb[m,N] = bf16(gelu_exact(acc+bias))
// MODE 3: ADD  -> Cf[m,N] += acc + bias               (FFN2 accumulate into x)
template<int MODE>
__global__ __launch_bounds__(512,2) void gemm_bt(
    const unsigned short* __restrict__ A, const unsigned short* __restrict__ Bw,
    const float* __restrict__ bias, const float* __restrict__ extra,
    float* __restrict__ Cf, unsigned short* __restrict__ Cb,
    int M, int N, int K)
{
  // [buf][half][128][64] bf16 each; 64KB + 64KB = 128KB LDS
  __shared__ __align__(16) unsigned short As[2*2*128*64];
  __shared__ __align__(16) unsigned short Bs[2*2*128*64];
  const int tid  = threadIdx.x;
  const int lane = tid & 63, wave = tid >> 6;
  const int wm = wave >> 2, wn = wave & 3;      // 2x4 wave grid
  // XCD-aware bijective remap (total blocks divisible by 8)
  const int gx  = gridDim.x;
  const int f   = blockIdx.y * gx + blockIdx.x;
  const int xcd = f & 7, kk = f >> 3;
  const int nx  = kk % gx;
  const int ny  = (kk / gx) * 8 + xcd;
  const int m0 = ny*256, n0 = nx*256;
  // staging geometry: call covers 64 rows; wave w writes rows w*8..w*8+7
  const int r8  = lane >> 3;                    // row within wave's 8-row chunk
  const int gch = ((lane & 7) ^ r8) * 8;        // pre-swizzled global k-chunk (elems)
  // fragment-read geometry
  const int l15 = lane & 15;
  const int kc  = lane >> 4, x7 = lane & 7;
  const int ch0 = ( kc      ^ x7) * 8;          // swizzled LDS chunk, k-slice 0
  const int ch1 = ((kc + 4) ^ x7) * 8;          // k-slice 1
  const int NT  = K >> 6;

  f32x4 acc[2][2][4][2];
  #pragma unroll
  for(int a0=0;a0<2;a0++)
    #pragma unroll
    for(int a1=0;a1<2;a1++)
      #pragma unroll
      for(int a2=0;a2<4;a2++)
        #pragma unroll
        for(int a3=0;a3<2;a3++) acc[a0][a1][a2][a3]=(f32x4)(0.f);

  auto stageA = [&](int h, int bb, int kcol){
    const unsigned short* g = A + (size_t)(m0 + h*128 + wave*8 + r8)*K + kcol + gch;
    unsigned short* l = &As[((bb*2 + h)*128 + wave*8)*64];
    async16(g, l);
    async16(g + (size_t)64*K, l + 64*64);
  };
  auto stageB = [&](int h, int bb, int kcol){
    const unsigned short* g = Bw + (size_t)(n0 + h*128 + wave*8 + r8)*K + kcol + gch;
    unsigned short* l = &Bs[((bb*2 + h)*128 + wave*8)*64];
    async16(g, l);
    async16(g + (size_t)64*K, l + 64*64);
  };

  #define READ_A(H,BB) { const unsigned short* Ab=&As[((BB)*2+(H))*128*64];         \
    _Pragma("unroll") for(int fi=0;fi<4;fi++){ int ro=(wm*64+fi*16+l15)*64;          \
      af[fi][0]=*(const short8*)&Ab[ro+ch0];                                         \
      af[fi][1]=*(const short8*)&Ab[ro+ch1]; } }
  #define READ_B(H,BB,DST) { const unsigned short* Bb=&Bs[((BB)*2+(H))*128*64];      \
    _Pragma("unroll") for(int ni=0;ni<2;ni++){ int ro=(wn*32+ni*16+l15)*64;          \
      DST[ni][0]=*(const short8*)&Bb[ro+ch0];                                        \
      DST[ni][1]=*(const short8*)&Bb[ro+ch1]; } }
  #define QUAD(MQ,NQ,BV) {                                                           \
    _Pragma("unroll") for(int fi=0;fi<4;fi++)                                        \
      _Pragma("unroll") for(int ni=0;ni<2;ni++){                                     \
        acc[MQ][NQ][fi][ni]=__builtin_amdgcn_mfma_f32_16x16x32_bf16(                 \
            af[fi][0],BV[ni][0],acc[MQ][NQ][fi][ni],0,0,0);                          \
        acc[MQ][NQ][fi][ni]=__builtin_amdgcn_mfma_f32_16x16x32_bf16(                 \
            af[fi][1],BV[ni][1],acc[MQ][NQ][fi][ni],0,0,0); } }

  // prologue: tile0 fully, tile1 Ah0/Bh0; wait tile0 (keep 2 halves in flight)
  stageA(0,0,0); stageA(1,0,0); stageB(0,0,0); stageB(1,0,0);
  if(NT>1){
    stageA(0,1,64); stageB(0,1,64);
    asm volatile("s_waitcnt vmcnt(4)" ::: "memory");
  } else {
    asm volatile("s_waitcnt vmcnt(0)" ::: "memory");
  }
  __builtin_amdgcn_s_barrier();

  for(int t=0; t<NT; ++t){
    const int bi = t & 1, bo = (t+1) & 1;
    const int k1 = (t+1) << 6, k2 = (t+2) << 6;
    short8 af[4][2], b0v[2][2], b1v[2][2];

    // phase 0: quad(0,0)
    READ_A(0,bi); READ_B(0,bi,b0v);
    if(t+1<NT) stageA(1,bo,k1);
    __builtin_amdgcn_s_barrier();
    asm volatile("s_waitcnt lgkmcnt(0)" ::: "memory");
    __builtin_amdgcn_s_setprio(1); QUAD(0,0,b0v); __builtin_amdgcn_s_setprio(0);
    __builtin_amdgcn_s_barrier();

    // phase 1: quad(0,1)  (af reused)
    READ_B(1,bi,b1v);
    if(t+1<NT) stageB(1,bo,k1);
    __builtin_amdgcn_s_barrier();
    asm volatile("s_waitcnt lgkmcnt(0)" ::: "memory");
    __builtin_amdgcn_s_setprio(1); QUAD(0,1,b1v); __builtin_amdgcn_s_setprio(0);
    __builtin_amdgcn_s_barrier();

    // phase 2: quad(1,0)  (b0v reused)
    READ_A(1,bi);
    if(t+2<NT) stageA(0,bi,k2);
    __builtin_amdgcn_s_barrier();
    asm volatile("s_waitcnt lgkmcnt(0)" ::: "memory");
    __builtin_amdgcn_s_setprio(1); QUAD(1,0,b0v); __builtin_amdgcn_s_setprio(0);
    __builtin_amdgcn_s_barrier();

    // phase 3: quad(1,1)  (af + b1v reused, no ds_read)
    if(t+2<NT) stageB(0,bi,k2);
    __builtin_amdgcn_s_barrier();
    asm volatile("s_waitcnt lgkmcnt(0)" ::: "memory");
    __builtin_amdgcn_s_setprio(1); QUAD(1,1,b1v); __builtin_amdgcn_s_setprio(0);
    // boundary: counted vmcnt, never 0 in steady state
    if(t+2<NT){ asm volatile("s_waitcnt vmcnt(4)" ::: "memory"); }
    else      { asm volatile("s_waitcnt vmcnt(0)" ::: "memory"); }
    __builtin_amdgcn_s_barrier();
  }
  #undef READ_A
  #undef READ_B
  #undef QUAD

  // epilogue: C/D layout col=lane&15, row=(lane>>4)*4+reg
  const int rb0 = (lane>>4)*4;
  #pragma unroll
  for(int mq=0;mq<2;mq++){
    #pragma unroll
    for(int fi=0;fi<4;fi++){
      #pragma unroll
      for(int i=0;i<4;i++){
        int m = m0 + mq*128 + wm*64 + fi*16 + rb0 + i;
        float valid = (MODE==0) ? extra[m] : 0.f;
        #pragma unroll
        for(int nq=0;nq<2;nq++){
          #pragma unroll
          for(int ni=0;ni<2;ni++){
            int n = n0 + nq*128 + wn*32 + ni*16 + l15;
            float v = acc[mq][nq][fi][ni][i] + bias[n];
            if(MODE==0){
              int part = n>>10;                      // 0=q,1=k,2=v
              float p = (v>0.f)? (v+1.f) : __expf(v);// phi = elu+1
              float r = (part==0)? p : (part==1? p*valid : v*valid);
              Cb[(size_t)m*N + n] = f2b(r);
            } else if(MODE==1){
              size_t off=(size_t)m*N+n;
              Cf[off] = v + extra[off];
            } else if(MODE==2){
              float gl = 0.5f*v*(1.f+erff(v*0.70710678118654752f));
              Cb[(size_t)m*N+n] = f2b(gl);
            } else {
              size_t off=(size_t)m*N+n;
              Cf[off] += v;
            }
          }
        }
      }
    }
  }
}

// ---------------- kv = phi(k)^T v, z = sum phi(k), partial over 256-row chunks ----
__global__ __launch_bounds__(256) void kvz_partial_kernel(
    const unsigned short* __restrict__ qkv, float* __restrict__ kvp, float* __restrict__ zp)
{
  const int chunk = blockIdx.x;   // 0..15 (256 rows each)
  const int bh = blockIdx.y;      // 0..127
  const int b = bh>>4, h = bh&15;
  const int t = threadIdx.x;
  __shared__ float kfs[16][64];
  __shared__ float vs[16][64];
  float acc[4][4]={{0}}; float zacc[4]={0};
  const int td=t&15, te=t>>4;
  const int d0=td*4, e0=te*4;
  const int lr=t>>4, lc=(t&15)*4;
  for(int s=0;s<16;s++){
    size_t m  = (size_t)(b*SEQ + chunk*256 + s*16 + lr);
    size_t rb = m*3072 + (size_t)h*64;
    ushort4 k4 = *(const ushort4*)(qkv + rb + 1024 + lc);
    ushort4 v4 = *(const ushort4*)(qkv + rb + 2048 + lc);
    __syncthreads();
    kfs[lr][lc]=b2f(k4.x); kfs[lr][lc+1]=b2f(k4.y); kfs[lr][lc+2]=b2f(k4.z); kfs[lr][lc+3]=b2f(k4.w);
    vs [lr][lc]=b2f(v4.x); vs [lr][lc+1]=b2f(v4.y); vs [lr][lc+2]=b2f(v4.z); vs [lr][lc+3]=b2f(v4.w);
    __syncthreads();
    #pragma unroll
    for(int n=0;n<16;n++){
      float4 kq=*(const float4*)&kfs[n][d0];
      float4 vv=*(const float4*)&vs[n][e0];
      float kqa[4]={kq.x,kq.y,kq.z,kq.w};
      float vva[4]={vv.x,vv.y,vv.z,vv.w};
      #pragma unroll
      for(int i=0;i<4;i++)
        #pragma unroll
        for(int j=0;j<4;j++) acc[i][j]+=kqa[i]*vva[j];
      if(te==0){ zacc[0]+=kq.x; zacc[1]+=kq.y; zacc[2]+=kq.z; zacc[3]+=kq.w; }
    }
  }
  const int pidx = bh*16 + chunk;
  float* kvd = kvp + (size_t)pidx*4096;
  #pragma unroll
  for(int i=0;i<4;i++){
    float4 o={acc[i][0],acc[i][1],acc[i][2],acc[i][3]};
    *(float4*)(kvd + (d0+i)*64 + e0)=o;
  }
  if(te==0){
    float4 o={zacc[0],zacc[1],zacc[2],zacc[3]};
    *(float4*)(zp + (size_t)pidx*64 + d0)=o;
  }
}

__global__ void kvz_reduce_kernel(const float* __restrict__ kvp, const float* __restrict__ zp,
                                  float* __restrict__ kv, float* __restrict__ z){
  int bh = blockIdx.x, t = threadIdx.x;
  for(int j=t; j<4096; j+=256){
    float s=0;
    for(int c=0;c<16;c++) s += kvp[((size_t)bh*16+c)*4096 + j];
    kv[(size_t)bh*4096 + j] = s;
  }
  if(t<64){
    float s=0;
    for(int c=0;c<16;c++) s += zp[((size_t)bh*16+c)*64 + t];
    z[bh*64+t]=s;
  }
}

// ---------------- y = (qf @ kv) / max(qf . z, eps) -> bf16 [MTOK, 1024] ----------
__global__ __launch_bounds__(256) void y_kernel(
    const unsigned short* __restrict__ qkv, const float* __restrict__ kv,
    const float* __restrict__ z, unsigned short* __restrict__ ybuf)
{
  const int nch = blockIdx.x;   // 0..63 (64 rows each)
  const int bh  = blockIdx.y;   // 0..127
  const int b = bh>>4, h = bh&15;
  const int t = threadIdx.x;
  __shared__ float kvs[64][64];
  __shared__ float qfs[64][68];  // padded: breaks 4-way bank conflict on column reads
  __shared__ float zs[64];
  // stage kv (fp32) and z
  for(int j=t*4; j<4096; j+=1024){
    float4 vv=*(const float4*)(kv+(size_t)bh*4096+j);
    ((float*)kvs)[j]=vv.x; ((float*)kvs)[j+1]=vv.y; ((float*)kvs)[j+2]=vv.z; ((float*)kvs)[j+3]=vv.w;
  }
  if(t<64) zs[t]=z[bh*64+t];
  // stage qf tile (64 rows x 64 d)
  for(int s=0;s<4;s++){
    int row=s*16+(t>>4), col=(t&15)*4;
    size_t m=(size_t)(b*SEQ+nch*64+row);
    ushort4 q4=*(const ushort4*)(qkv+m*3072+(size_t)h*64+col);
    qfs[row][col]=b2f(q4.x); qfs[row][col+1]=b2f(q4.y); qfs[row][col+2]=b2f(q4.z); qfs[row][col+3]=b2f(q4.w);
  }
  __syncthreads();
  const int tn=t>>4, te=t&15;
  const int nr0=tn*4, e0=te*4;
  float acc[4][4]={{0}}; float den[4]={0};
  #pragma unroll 4
  for(int d=0;d<64;d++){
    float4 kv4=*(const float4*)&kvs[d][e0];
    float zd=zs[d];
    #pragma unroll
    for(int i=0;i<4;i++){
      float q=qfs[nr0+i][d];
      acc[i][0]+=q*kv4.x; acc[i][1]+=q*kv4.y; acc[i][2]+=q*kv4.z; acc[i][3]+=q*kv4.w;
      den[i]+=q*zd;
    }
  }
  #pragma unroll
  for(int i=0;i<4;i++){
    float inv=1.f/fmaxf(den[i],1e-6f);
    ushort4 o;
    o.x=f2b(acc[i][0]*inv); o.y=f2b(acc[i][1]*inv); o.z=f2b(acc[i][2]*inv); o.w=f2b(acc[i][3]*inv);
    size_t m=(size_t)(b*SEQ+nch*64+nr0+i);
    *(ushort4*)(ybuf+m*1024+(size_t)h*64+e0)=o;
  }
}

extern "C" void kernel_launch(void* const* d_in, const int* in_sizes, int n_in,
                              void* d_out, int out_size, void* d_ws, size_t ws_size,
                              hipStream_t stream)
{
  const float* src   = (const float*)d_in[0];
  const void*  mask  = d_in[1];
  const float* qkv_w = (const float*)d_in[2];
  const float* qkv_b = (const float*)d_in[3];
  const float* out_w = (const float*)d_in[4];
  const float* out_b = (const float*)d_in[5];
  const float* w1    = (const float*)d_in[6];
  const float* b1    = (const float*)d_in[7];
  const float* w2    = (const float*)d_in[8];
  const float* b2    = (const float*)d_in[9];
  const float* ln1g  = (const float*)d_in[10];
  const float* ln1b  = (const float*)d_in[11];
  const float* ln2g  = (const float*)d_in[12];
  const float* ln2b  = (const float*)d_in[13];
  float* out = (float*)d_out;
  char* ws = (char*)d_ws;

  // workspace layout (~346 MiB total)
  size_t o = 0;
  int* flag = (int*)(ws);                         o += 256;
  float* validf = (float*)(ws+o);                 o += (size_t)MTOK*4;
  unsigned short* wqb = (unsigned short*)(ws+o);  o += (size_t)3072*1024*2;
  unsigned short* wob = (unsigned short*)(ws+o);  o += (size_t)1024*1024*2;
  unsigned short* w1b = (unsigned short*)(ws+o);  o += (size_t)4096*1024*2;
  unsigned short* w2b = (unsigned short*)(ws+o);  o += (size_t)1024*4096*2;
  unsigned short* bufA = (unsigned short*)(ws+o); o += (size_t)MTOK*1024*2;       // ln1 -> y -> ln2
  char* R = ws+o;                                 o += (size_t)MTOK*4096*2;       // qkv (201MB) then h (268MB)
  unsigned short* qkvbuf = (unsigned short*)R;
  float* kvp = (float*)(R + (size_t)MTOK*3072*2);                                  // fits in R tail
  float* zp  = (float*)(R + (size_t)MTOK*3072*2 + (size_t)2048*4096*4);
  unsigned short* hbuf = (unsigned short*)R;
  float* kv = (float*)(ws+o);                     o += (size_t)128*4096*4;
  float* zv = (float*)(ws+o);                     o += (size_t)128*64*4;

  detect_mask_kernel<<<1,256,0,stream>>>((const unsigned int*)mask, flag);
  decode_mask_kernel<<<MTOK/256,256,0,stream>>>(mask, flag, validf);
  cast_bf16_kernel<<<3072,256,0,stream>>>(qkv_w, wqb, 3072*1024);
  cast_bf16_kernel<<<1024,256,0,stream>>>(out_w, wob, 1024*1024);
  cast_bf16_kernel<<<4096,256,0,stream>>>(w1,  w1b, 4096*1024);
  cast_bf16_kernel<<<8192,256,0,stream>>>(w2,  w2b, 1024*4096);

  ln_kernel<<<MTOK,256,0,stream>>>(src, ln1g, ln1b, bufA);
  gemm_bt<0><<<dim3(3072/256, MTOK/256),512,0,stream>>>(bufA, wqb, qkv_b, validf, nullptr, qkvbuf, MTOK,3072,1024);
  kvz_partial_kernel<<<dim3(16,128),256,0,stream>>>(qkvbuf, kvp, zp);
  kvz_reduce_kernel<<<128,256,0,stream>>>(kvp, zp, kv, zv);
  y_kernel<<<dim3(64,128),256,0,stream>>>(qkvbuf, kv, zv, bufA);
  gemm_bt<1><<<dim3(1024/256, MTOK/256),512,0,stream>>>(bufA, wob, out_b, src, out, nullptr, MTOK,1024,1024);
  ln_kernel<<<MTOK,256,0,stream>>>(out, ln2g, ln2b, bufA);
  gemm_bt<2><<<dim3(4096/256, MTOK/256),512,0,stream>>>(bufA, w1b, b1, nullptr, nullptr, hbuf, MTOK,4096,1024);
  gemm_bt<3><<<dim3(1024/256, MTOK/256),512,0,stream>>>(hbuf, w2b, b2, nullptr, out, nullptr, MTOK,1024,4096);
}

// Round 2
// 1488.188 us; speedup vs baseline: 1.0487x; 1.0487x over previous
//
#include <hip/hip_runtime.h>
#include <cmath>
#include <cstdint>

// Problem constants (B=8, N=4096, C=1024, H=16, D=64, FF=4096)
#define MTOK 32768   // B*N tokens
#define CDIM 1024
#define SEQ  4096
#define NHEAD 16
#define HDIM 64
#define FFDIM 4096

typedef __attribute__((ext_vector_type(8))) short short8;   // 8 bf16 (4 VGPRs)
typedef __attribute__((ext_vector_type(4))) float f32x4;

static __device__ __forceinline__ float b2f(unsigned short u){
  union { unsigned int i; float f; } c; c.i = ((unsigned int)u)<<16; return c.f;
}
static __device__ __forceinline__ unsigned short f2b(float f){
  union { float f; unsigned int i; } c; c.f = f;
  return (unsigned short)((c.i + 0x7fffu + ((c.i>>16)&1u)) >> 16);  // RNE
}
// async global->LDS, 16B/lane; LDS dest = wave-uniform base + lane*16
static __device__ __forceinline__ void async16(const void* g, void* l){
  __builtin_amdgcn_global_load_lds((const __attribute__((address_space(1))) void*)g,
                                   (__attribute__((address_space(3))) void*)l, 16, 0, 0);
}

// ---------------- mask dtype detection + decode ----------------
__global__ void detect_mask_kernel(const unsigned int* __restrict__ m, int* __restrict__ flag){
  __shared__ int any;
  if(threadIdx.x==0) any=0;
  __syncthreads();
  int loc=0;
  for(int i=threadIdx.x;i<8192;i+=256) if(m[i]>1u) loc=1;
  if(loc) atomicOr(&any,1);
  __syncthreads();
  if(threadIdx.x==0) *flag=any;
}
__global__ void decode_mask_kernel(const void* __restrict__ m, const int* __restrict__ flag,
                                   float* __restrict__ validf){
  int i = blockIdx.x*256 + threadIdx.x;   // grid covers MTOK exactly
  int pad = (*flag) ? (int)((const unsigned char*)m)[i] : ((const int*)m)[i];
  validf[i] = pad ? 0.f : 1.f;
}

// ---------------- fp32 -> bf16 cast (weights) ----------------
__global__ void cast_bf16_kernel(const float* __restrict__ x, unsigned short* __restrict__ y, int n){
  int i = (blockIdx.x*256 + threadIdx.x)*4;
  if(i>=n) return;
  float4 v = *(const float4*)(x+i);
  ushort4 o; o.x=f2b(v.x); o.y=f2b(v.y); o.z=f2b(v.z); o.w=f2b(v.w);
  *(ushort4*)(y+i)=o;
}

// ---------------- LayerNorm (C=1024) -> bf16 ----------------
__global__ __launch_bounds__(256) void ln_kernel(const float* __restrict__ x,
    const float* __restrict__ g, const float* __restrict__ bt, unsigned short* __restrict__ out){
  int row = blockIdx.x, t = threadIdx.x;
  const float* xr = x + (size_t)row*CDIM;
  float4 v = *(const float4*)(xr + t*4);
  float s1 = v.x+v.y+v.z+v.w;
  float s2 = v.x*v.x+v.y*v.y+v.z*v.z+v.w*v.w;
  #pragma unroll
  for(int off=32; off>0; off>>=1){ s1+=__shfl_down(s1,off); s2+=__shfl_down(s2,off); }
  __shared__ float a1[4], a2[4];
  __shared__ float mu_s, rs_s;
  if((t&63)==0){ a1[t>>6]=s1; a2[t>>6]=s2; }
  __syncthreads();
  if(t==0){
    float u1=a1[0]+a1[1]+a1[2]+a1[3], u2=a2[0]+a2[1]+a2[2]+a2[3];
    float mu=u1*(1.f/CDIM);
    mu_s=mu; rs_s=rsqrtf(u2*(1.f/CDIM)-mu*mu+1e-5f);
  }
  __syncthreads();
  float mu=mu_s, rs=rs_s;
  float4 gg=*(const float4*)(g+t*4), bb=*(const float4*)(bt+t*4);
  ushort4 o;
  o.x=f2b((v.x-mu)*rs*gg.x+bb.x);
  o.y=f2b((v.y-mu)*rs*gg.y+bb.y);
  o.z=f2b((v.z-mu)*rs*gg.z+bb.z);
  o.w=f2b((v.w-mu)*rs*gg.w+bb.w);
  *(ushort4*)(out+(size_t)row*CDIM+t*4)=o;
}

// ---------------- GEMM: C[M,N] = A[M,K] * Bw[N,K]^T, bf16 in, fused epilogue ----
// 256x256 tile, BK=64, 512 threads (8 waves, 2x4), m201-faithful 8-phase schedule:
// per K-tile t, 4 phases = C-quadrants q00,q01,q10,q11; each phase stages ONE
// half-tile at its earliest hazard-free slot:
//   ph1 (q00, reads A0(t),B0(t), 12 ds_read): stage B1(t+1)   [B1(t-1) last read ph2 of t-1]
//   ph2 (q01, reads B1(t),       4 ds_read): stage A0(t+2)   [A0(t)   last read ph1]
//   ph3 (q10, reads A1(t),       8 ds_read): stage B0(t+2)   [B0(t)   last read ph1]
//   ph4 (q11, no reads               ): stage A1(t+2)   [A1(t)   last read ph3]
// Boundary: single s_waitcnt vmcnt(6) per K-tile — drains exactly tile t+1's 4
// half-tiles (each issued >=3 phases earlier), keeps {A0,B0,A1}(t+2) in flight.
// Counted vmcnt never 0 in steady state (T3+T4); setprio around MFMA (T5);
// XOR-chunk LDS swizzle, pre-swizzled global src (T2, conflict-free);
// XCD-aware bijective block remap (T1, total blocks % 8 == 0 for all launches).
// MODE 0: QKV  -> Cb[m,3072] = phi/mask per column third (extra=validf, bias=qkv_b)
// MODE 1: XRES -> Cf[m,N] = acc + bias + extra[m,N]   (out-proj + residual, Cf=d_out)
// MODE 2: GELU -> Cb[m,N] = bf16(gelu_exact(acc+bias))
// MODE 3: ADD  -> Cf[m,N] += acc + bias               (FFN2 accumulate into x)
template<int MODE, int KDIM>
__global__ __launch_bounds__(512,2) void gemm_bt(
    const unsigned short* __restrict__ A, const unsigned short* __restrict__ Bw,
    const float* __restrict__ bias, const float* __restrict__ extra,
    float* __restrict__ Cf, unsigned short* __restrict__ Cb,
    int M, int N)
{
  // [buf][half][128][64] bf16 each; 64KB + 64KB = 128KB LDS
  __shared__ __align__(16) unsigned short As[2*2*128*64];
  __shared__ __align__(16) unsigned short Bs[2*2*128*64];
  const int tid  = threadIdx.x;
  const int lane = tid & 63, wave = tid >> 6;
  const int wm = wave >> 2, wn = wave & 3;      // 2x4 wave grid
  // XCD-aware bijective remap (total blocks divisible by 8)
  const int gx  = gridDim.x;
  const int f   = blockIdx.y * gx + blockIdx.x;
  const int xcd = f & 7, kk = f >> 3;
  const int nx  = kk % gx;
  const int ny  = (kk / gx) * 8 + xcd;
  const int m0 = ny*256, n0 = nx*256;
  // staging geometry: one stage call covers 128 rows (2 x async16 per thread)
  const int r8  = lane >> 3;                    // row within wave's 8-row chunk
  const int gch = ((lane & 7) ^ r8) * 8;        // pre-swizzled global k-chunk (elems)
  const unsigned short* gA = A  + (size_t)(m0 + wave*8 + r8)*KDIM + gch;
  const unsigned short* gB = Bw + (size_t)(n0 + wave*8 + r8)*KDIM + gch;
  // fragment-read geometry
  const int l15 = lane & 15;
  const int kc  = lane >> 4, x7 = lane & 7;
  const int ch0 = ( kc      ^ x7) * 8;          // swizzled LDS chunk, k-slice 0
  const int ch1 = ((kc + 4) ^ x7) * 8;          // k-slice 1
  const int NT  = KDIM >> 6;

  f32x4 acc[2][2][4][2];
  #pragma unroll
  for(int a0=0;a0<2;a0++)
    #pragma unroll
    for(int a1=0;a1<2;a1++)
      #pragma unroll
      for(int a2=0;a2<4;a2++)
        #pragma unroll
        for(int a3=0;a3<2;a3++) acc[a0][a1][a2][a3]=(f32x4)(0.f);

  auto stA = [&](int h, int bb, int kcol){
    const unsigned short* g = gA + (size_t)h*128*KDIM + kcol;
    unsigned short* l = &As[((bb*2 + h)*128 + wave*8)*64];
    async16(g, l);
    async16(g + (size_t)64*KDIM, l + 4096);
  };
  auto stB = [&](int h, int bb, int kcol){
    const unsigned short* g = gB + (size_t)h*128*KDIM + kcol;
    unsigned short* l = &Bs[((bb*2 + h)*128 + wave*8)*64];
    async16(g, l);
    async16(g + (size_t)64*KDIM, l + 4096);
  };

  #define READ_A(H,BB) { const unsigned short* Ab=&As[((BB)*2+(H))*128*64];         \
    _Pragma("unroll") for(int fi=0;fi<4;fi++){ int ro=(wm*64+fi*16+l15)*64;          \
      af[fi][0]=*(const short8*)&Ab[ro+ch0];                                         \
      af[fi][1]=*(const short8*)&Ab[ro+ch1]; } }
  #define READ_B(H,BB,DST) { const unsigned short* Bb=&Bs[((BB)*2+(H))*128*64];      \
    _Pragma("unroll") for(int ni=0;ni<2;ni++){ int ro=(wn*32+ni*16+l15)*64;          \
      DST[ni][0]=*(const short8*)&Bb[ro+ch0];                                        \
      DST[ni][1]=*(const short8*)&Bb[ro+ch1]; } }
  #define QUAD(MQ,NQ,BV) {                                                           \
    _Pragma("unroll") for(int fi=0;fi<4;fi++)                                        \
      _Pragma("unroll") for(int ni=0;ni<2;ni++){                                     \
        acc[MQ][NQ][fi][ni]=__builtin_amdgcn_mfma_f32_16x16x32_bf16(                 \
            af[fi][0],BV[ni][0],acc[MQ][NQ][fi][ni],0,0,0);                          \
        acc[MQ][NQ][fi][ni]=__builtin_amdgcn_mfma_f32_16x16x32_bf16(                 \
            af[fi][1],BV[ni][1],acc[MQ][NQ][fi][ni],0,0,0); } }

  // prologue: tile0 fully + {A0,B0,A1}(1); drain tile0, keep 3 half-tiles in flight
  stA(0,0,0); stB(0,0,0); stB(1,0,0); stA(1,0,0);
  if(NT>1){
    stA(0,1,64); stB(0,1,64); stA(1,1,64);
    asm volatile("s_waitcnt vmcnt(6)" ::: "memory");
  } else {
    asm volatile("s_waitcnt vmcnt(0)" ::: "memory");
  }
  __builtin_amdgcn_s_barrier();

  for(int t=0; t<NT; ++t){
    const int bi = t & 1, bo = bi ^ 1;
    const int k1 = (t+1) << 6, k2 = (t+2) << 6;
    short8 af[4][2], b0v[2][2], b1v[2][2];

    // phase 1: q00 — reads A0,B0(t); stage B1(t+1)
    READ_A(0,bi); READ_B(0,bi,b0v);
    if(t+1<NT) stB(1,bo,k1);
    asm volatile("s_waitcnt lgkmcnt(8)");
    __builtin_amdgcn_s_barrier();
    asm volatile("s_waitcnt lgkmcnt(0)");
    __builtin_amdgcn_s_setprio(1); QUAD(0,0,b0v); __builtin_amdgcn_s_setprio(0);
    __builtin_amdgcn_s_barrier();

    // phase 2: q01 — reads B1(t); stage A0(t+2)  (af reused)
    READ_B(1,bi,b1v);
    if(t+2<NT) stA(0,bi,k2);
    __builtin_amdgcn_s_barrier();
    asm volatile("s_waitcnt lgkmcnt(0)");
    __builtin_amdgcn_s_setprio(1); QUAD(0,1,b1v); __builtin_amdgcn_s_setprio(0);
    __builtin_amdgcn_s_barrier();

    // phase 3: q10 — reads A1(t); stage B0(t+2)  (b0v reused)
    READ_A(1,bi);
    if(t+2<NT) stB(0,bi,k2);
    __builtin_amdgcn_s_barrier();
    asm volatile("s_waitcnt lgkmcnt(0)");
    __builtin_amdgcn_s_setprio(1); QUAD(1,0,b0v); __builtin_amdgcn_s_setprio(0);
    __builtin_amdgcn_s_barrier();

    // phase 4: q11 — no reads; stage A1(t+2)  (af + b1v reused)
    if(t+2<NT) stA(1,bi,k2);
    __builtin_amdgcn_s_barrier();
    __builtin_amdgcn_s_setprio(1); QUAD(1,1,b1v); __builtin_amdgcn_s_setprio(0);
    // boundary: counted vmcnt, never 0 in steady state; drains tile t+1 exactly
    if(t+2<NT){ asm volatile("s_waitcnt vmcnt(6)" ::: "memory"); }
    else      { asm volatile("s_waitcnt vmcnt(0)" ::: "memory"); }
    __builtin_amdgcn_sched_barrier(0);
    __builtin_amdgcn_s_barrier();
  }
  #undef READ_A
  #undef READ_B
  #undef QUAD

  // epilogue: C/D layout col=lane&15, row=(lane>>4)*4+reg
  const int rb0 = (lane>>4)*4;
  #pragma unroll
  for(int mq=0;mq<2;mq++){
    #pragma unroll
    for(int fi=0;fi<4;fi++){
      #pragma unroll
      for(int i=0;i<4;i++){
        int m = m0 + mq*128 + wm*64 + fi*16 + rb0 + i;
        float valid = (MODE==0) ? extra[m] : 0.f;
        #pragma unroll
        for(int nq=0;nq<2;nq++){
          #pragma unroll
          for(int ni=0;ni<2;ni++){
            int n = n0 + nq*128 + wn*32 + ni*16 + l15;
            float v = acc[mq][nq][fi][ni][i] + bias[n];
            if(MODE==0){
              int part = n>>10;                      // 0=q,1=k,2=v
              float p = (v>0.f)? (v+1.f) : __expf(v);// phi = elu+1
              float r = (part==0)? p : (part==1? p*valid : v*valid);
              Cb[(size_t)m*N + n] = f2b(r);
            } else if(MODE==1){
              size_t off=(size_t)m*N+n;
              Cf[off] = v + extra[off];
            } else if(MODE==2){
              float gl = 0.5f*v*(1.f+erff(v*0.70710678118654752f));
              Cb[(size_t)m*N+n] = f2b(gl);
            } else {
              size_t off=(size_t)m*N+n;
              Cf[off] += v;
            }
          }
        }
      }
    }
  }
}

// ---------------- kv = phi(k)^T v, z = sum phi(k), partial over 256-row chunks ----
__global__ __launch_bounds__(256) void kvz_partial_kernel(
    const unsigned short* __restrict__ qkv, float* __restrict__ kvp, float* __restrict__ zp)
{
  const int chunk = blockIdx.x;   // 0..15 (256 rows each)
  const int bh = blockIdx.y;      // 0..127
  const int b = bh>>4, h = bh&15;
  const int t = threadIdx.x;
  __shared__ float kfs[16][64];
  __shared__ float vs[16][64];
  float acc[4][4]={{0}}; float zacc[4]={0};
  const int td=t&15, te=t>>4;
  const int d0=td*4, e0=te*4;
  const int lr=t>>4, lc=(t&15)*4;
  for(int s=0;s<16;s++){
    size_t m  = (size_t)(b*SEQ + chunk*256 + s*16 + lr);
    size_t rb = m*3072 + (size_t)h*64;
    ushort4 k4 = *(const ushort4*)(qkv + rb + 1024 + lc);
    ushort4 v4 = *(const ushort4*)(qkv + rb + 2048 + lc);
    __syncthreads();
    kfs[lr][lc]=b2f(k4.x); kfs[lr][lc+1]=b2f(k4.y); kfs[lr][lc+2]=b2f(k4.z); kfs[lr][lc+3]=b2f(k4.w);
    vs [lr][lc]=b2f(v4.x); vs [lr][lc+1]=b2f(v4.y); vs [lr][lc+2]=b2f(v4.z); vs [lr][lc+3]=b2f(v4.w);
    __syncthreads();
    #pragma unroll
    for(int n=0;n<16;n++){
      float4 kq=*(const float4*)&kfs[n][d0];
      float4 vv=*(const float4*)&vs[n][e0];
      float kqa[4]={kq.x,kq.y,kq.z,kq.w};
      float vva[4]={vv.x,vv.y,vv.z,vv.w};
      #pragma unroll
      for(int i=0;i<4;i++)
        #pragma unroll
        for(int j=0;j<4;j++) acc[i][j]+=kqa[i]*vva[j];
      if(te==0){ zacc[0]+=kq.x; zacc[1]+=kq.y; zacc[2]+=kq.z; zacc[3]+=kq.w; }
    }
  }
  const int pidx = bh*16 + chunk;
  float* kvd = kvp + (size_t)pidx*4096;
  #pragma unroll
  for(int i=0;i<4;i++){
    float4 o={acc[i][0],acc[i][1],acc[i][2],acc[i][3]};
    *(float4*)(kvd + (d0+i)*64 + e0)=o;
  }
  if(te==0){
    float4 o={zacc[0],zacc[1],zacc[2],zacc[3]};
    *(float4*)(zp + (size_t)pidx*64 + d0)=o;
  }
}

__global__ void kvz_reduce_kernel(const float* __restrict__ kvp, const float* __restrict__ zp,
                                  float* __restrict__ kv, float* __restrict__ z){
  int bh = blockIdx.x, t = threadIdx.x;
  for(int j=t; j<4096; j+=256){
    float s=0;
    for(int c=0;c<16;c++) s += kvp[((size_t)bh*16+c)*4096 + j];
    kv[(size_t)bh*4096 + j] = s;
  }
  if(t<64){
    float s=0;
    for(int c=0;c<16;c++) s += zp[((size_t)bh*16+c)*64 + t];
    z[bh*64+t]=s;
  }
}

// ---------------- y = (qf @ kv) / max(qf . z, eps) -> bf16 [MTOK, 1024] ----------
__global__ __launch_bounds__(256) void y_kernel(
    const unsigned short* __restrict__ qkv, const float* __restrict__ kv,
    const float* __restrict__ z, unsigned short* __restrict__ ybuf)
{
  const int nch = blockIdx.x;   // 0..63 (64 rows each)
  const int bh  = blockIdx.y;   // 0..127
  const int b = bh>>4, h = bh&15;
  const int t = threadIdx.x;
  __shared__ float kvs[64][64];
  __shared__ float qfs[64][68];  // padded: breaks 4-way bank conflict on column reads
  __shared__ float zs[64];
  // stage kv (fp32) and z
  for(int j=t*4; j<4096; j+=1024){
    float4 vv=*(const float4*)(kv+(size_t)bh*4096+j);
    ((float*)kvs)[j]=vv.x; ((float*)kvs)[j+1]=vv.y; ((float*)kvs)[j+2]=vv.z; ((float*)kvs)[j+3]=vv.w;
  }
  if(t<64) zs[t]=z[bh*64+t];
  // stage qf tile (64 rows x 64 d)
  for(int s=0;s<4;s++){
    int row=s*16+(t>>4), col=(t&15)*4;
    size_t m=(size_t)(b*SEQ+nch*64+row);
    ushort4 q4=*(const ushort4*)(qkv+m*3072+(size_t)h*64+col);
    qfs[row][col]=b2f(q4.x); qfs[row][col+1]=b2f(q4.y); qfs[row][col+2]=b2f(q4.z); qfs[row][col+3]=b2f(q4.w);
  }
  __syncthreads();
  const int tn=t>>4, te=t&15;
  const int nr0=tn*4, e0=te*4;
  float acc[4][4]={{0}}; float den[4]={0};
  #pragma unroll 4
  for(int d=0;d<64;d++){
    float4 kv4=*(const float4*)&kvs[d][e0];
    float zd=zs[d];
    #pragma unroll
    for(int i=0;i<4;i++){
      float q=qfs[nr0+i][d];
      acc[i][0]+=q*kv4.x; acc[i][1]+=q*kv4.y; acc[i][2]+=q*kv4.z; acc[i][3]+=q*kv4.w;
      den[i]+=q*zd;
    }
  }
  #pragma unroll
  for(int i=0;i<4;i++){
    float inv=1.f/fmaxf(den[i],1e-6f);
    ushort4 o;
    o.x=f2b(acc[i][0]*inv); o.y=f2b(acc[i][1]*inv); o.z=f2b(acc[i][2]*inv); o.w=f2b(acc[i][3]*inv);
    size_t m=(size_t)(b*SEQ+nch*64+nr0+i);
    *(ushort4*)(ybuf+m*1024+(size_t)h*64+e0)=o;
  }
}

extern "C" void kernel_launch(void* const* d_in, const int* in_sizes, int n_in,
                              void* d_out, int out_size, void* d_ws, size_t ws_size,
                              hipStream_t stream)
{
  const float* src   = (const float*)d_in[0];
  const void*  mask  = d_in[1];
  const float* qkv_w = (const float*)d_in[2];
  const float* qkv_b = (const float*)d_in[3];
  const float* out_w = (const float*)d_in[4];
  const float* out_b = (const float*)d_in[5];
  const float* w1    = (const float*)d_in[6];
  const float* b1    = (const float*)d_in[7];
  const float* w2    = (const float*)d_in[8];
  const float* b2    = (const float*)d_in[9];
  const float* ln1g  = (const float*)d_in[10];
  const float* ln1b  = (const float*)d_in[11];
  const float* ln2g  = (const float*)d_in[12];
  const float* ln2b  = (const float*)d_in[13];
  float* out = (float*)d_out;
  char* ws = (char*)d_ws;

  // workspace layout (~346 MiB total)
  size_t o = 0;
  int* flag = (int*)(ws);                         o += 256;
  float* validf = (float*)(ws+o);                 o += (size_t)MTOK*4;
  unsigned short* wqb = (unsigned short*)(ws+o);  o += (size_t)3072*1024*2;
  unsigned short* wob = (unsigned short*)(ws+o);  o += (size_t)1024*1024*2;
  unsigned short* w1b = (unsigned short*)(ws+o);  o += (size_t)4096*1024*2;
  unsigned short* w2b = (unsigned short*)(ws+o);  o += (size_t)1024*4096*2;
  unsigned short* bufA = (unsigned short*)(ws+o); o += (size_t)MTOK*1024*2;       // ln1 -> y -> ln2
  char* R = ws+o;                                 o += (size_t)MTOK*4096*2;       // qkv (201MB) then h (268MB)
  unsigned short* qkvbuf = (unsigned short*)R;
  float* kvp = (float*)(R + (size_t)MTOK*3072*2);                                  // fits in R tail
  float* zp  = (float*)(R + (size_t)MTOK*3072*2 + (size_t)2048*4096*4);
  unsigned short* hbuf = (unsigned short*)R;
  float* kv = (float*)(ws+o);                     o += (size_t)128*4096*4;
  float* zv = (float*)(ws+o);                     o += (size_t)128*64*4;

  detect_mask_kernel<<<1,256,0,stream>>>((const unsigned int*)mask, flag);
  decode_mask_kernel<<<MTOK/256,256,0,stream>>>(mask, flag, validf);
  cast_bf16_kernel<<<3072,256,0,stream>>>(qkv_w, wqb, 3072*1024);
  cast_bf16_kernel<<<1024,256,0,stream>>>(out_w, wob, 1024*1024);
  cast_bf16_kernel<<<4096,256,0,stream>>>(w1,  w1b, 4096*1024);
  cast_bf16_kernel<<<8192,256,0,stream>>>(w2,  w2b, 1024*4096);

  ln_kernel<<<MTOK,256,0,stream>>>(src, ln1g, ln1b, bufA);
  gemm_bt<0,1024><<<dim3(3072/256, MTOK/256),512,0,stream>>>(bufA, wqb, qkv_b, validf, nullptr, qkvbuf, MTOK,3072);
  kvz_partial_kernel<<<dim3(16,128),256,0,stream>>>(qkvbuf, kvp, zp);
  kvz_reduce_kernel<<<128,256,0,stream>>>(kvp, zp, kv, zv);
  y_kernel<<<dim3(64,128),256,0,stream>>>(qkvbuf, kv, zv, bufA);
  gemm_bt<1,1024><<<dim3(1024/256, MTOK/256),512,0,stream>>>(bufA, wob, out_b, src, out, nullptr, MTOK,1024);
  ln_kernel<<<MTOK,256,0,stream>>>(out, ln2g, ln2b, bufA);
  gemm_bt<2,1024><<<dim3(4096/256, MTOK/256),512,0,stream>>>(bufA, w1b, b1, nullptr, nullptr, hbuf, MTOK,4096);
  gemm_bt<3,4096><<<dim3(1024/256, MTOK/256),512,0,stream>>>(hbuf, w2b, b2, nullptr, out, nullptr, MTOK,1024);
}

// Round 3
// 1467.380 us; speedup vs baseline: 1.0635x; 1.0142x over previous
//
#include <hip/hip_runtime.h>
#include <cmath>
#include <cstdint>

// Problem constants (B=8, N=4096, C=1024, H=16, D=64, FF=4096)
#define MTOK 32768   // B*N tokens
#define CDIM 1024
#define SEQ  4096
#define NHEAD 16
#define HDIM 64
#define FFDIM 4096

typedef __attribute__((ext_vector_type(8))) short short8;   // 8 bf16 (4 VGPRs)
typedef __attribute__((ext_vector_type(4))) float f32x4;

static __device__ __forceinline__ float b2f(unsigned short u){
  union { unsigned int i; float f; } c; c.i = ((unsigned int)u)<<16; return c.f;
}
static __device__ __forceinline__ unsigned short f2b(float f){
  union { float f; unsigned int i; } c; c.f = f;
  return (unsigned short)((c.i + 0x7fffu + ((c.i>>16)&1u)) >> 16);  // RNE
}
// non-temporal (streaming) store: no-allocate hint so big C-writes don't evict
// A/B panels from L2/L3 during the K-loop of concurrent blocks
static __device__ __forceinline__ void nt_store_us(unsigned short v, unsigned short* p){
  __builtin_nontemporal_store(v, p);
}
static __device__ __forceinline__ void nt_store_f(float v, float* p){
  __builtin_nontemporal_store(v, p);
}
// async global->LDS, 16B/lane; LDS dest = wave-uniform base + lane*16
static __device__ __forceinline__ void async16(const void* g, void* l){
  __builtin_amdgcn_global_load_lds((const __attribute__((address_space(1))) void*)g,
                                   (__attribute__((address_space(3))) void*)l, 16, 0, 0);
}

// ---------------- mask dtype detection + decode ----------------
__global__ void detect_mask_kernel(const unsigned int* __restrict__ m, int* __restrict__ flag){
  __shared__ int any;
  if(threadIdx.x==0) any=0;
  __syncthreads();
  int loc=0;
  for(int i=threadIdx.x;i<8192;i+=256) if(m[i]>1u) loc=1;
  if(loc) atomicOr(&any,1);
  __syncthreads();
  if(threadIdx.x==0) *flag=any;
}
__global__ void decode_mask_kernel(const void* __restrict__ m, const int* __restrict__ flag,
                                   float* __restrict__ validf){
  int i = blockIdx.x*256 + threadIdx.x;   // grid covers MTOK exactly
  int pad = (*flag) ? (int)((const unsigned char*)m)[i] : ((const int*)m)[i];
  validf[i] = pad ? 0.f : 1.f;
}

// ---------------- fp32 -> bf16 cast, all four weights in one launch ----------------
__global__ void cast_all_kernel(const float* __restrict__ a, const float* __restrict__ b,
                                const float* __restrict__ c, const float* __restrict__ d,
                                unsigned short* __restrict__ oa, unsigned short* __restrict__ ob,
                                unsigned short* __restrict__ oc, unsigned short* __restrict__ od){
  long i = ((long)blockIdx.x*256 + threadIdx.x)*4;   // total 12582912 elems -> 12288 blocks
  const float* x; unsigned short* y; long off;
  if(i < 3145728){ x=a; y=oa; off=i; }
  else if(i < 4194304){ x=b; y=ob; off=i-3145728; }
  else if(i < 8388608){ x=c; y=oc; off=i-4194304; }
  else { x=d; y=od; off=i-8388608; }
  float4 v = *(const float4*)(x+off);
  ushort4 o; o.x=f2b(v.x); o.y=f2b(v.y); o.z=f2b(v.z); o.w=f2b(v.w);
  *(ushort4*)(y+off)=o;
}

// ---------------- LayerNorm (C=1024) -> bf16 ----------------
__global__ __launch_bounds__(256) void ln_kernel(const float* __restrict__ x,
    const float* __restrict__ g, const float* __restrict__ bt, unsigned short* __restrict__ out){
  int row = blockIdx.x, t = threadIdx.x;
  const float* xr = x + (size_t)row*CDIM;
  float4 v = *(const float4*)(xr + t*4);
  float s1 = v.x+v.y+v.z+v.w;
  float s2 = v.x*v.x+v.y*v.y+v.z*v.z+v.w*v.w;
  #pragma unroll
  for(int off=32; off>0; off>>=1){ s1+=__shfl_down(s1,off); s2+=__shfl_down(s2,off); }
  __shared__ float a1[4], a2[4];
  __shared__ float mu_s, rs_s;
  if((t&63)==0){ a1[t>>6]=s1; a2[t>>6]=s2; }
  __syncthreads();
  if(t==0){
    float u1=a1[0]+a1[1]+a1[2]+a1[3], u2=a2[0]+a2[1]+a2[2]+a2[3];
    float mu=u1*(1.f/CDIM);
    mu_s=mu; rs_s=rsqrtf(u2*(1.f/CDIM)-mu*mu+1e-5f);
  }
  __syncthreads();
  float mu=mu_s, rs=rs_s;
  float4 gg=*(const float4*)(g+t*4), bb=*(const float4*)(bt+t*4);
  ushort4 o;
  o.x=f2b((v.x-mu)*rs*gg.x+bb.x);
  o.y=f2b((v.y-mu)*rs*gg.y+bb.y);
  o.z=f2b((v.z-mu)*rs*gg.z+bb.z);
  o.w=f2b((v.w-mu)*rs*gg.w+bb.w);
  *(ushort4*)(out+(size_t)row*CDIM+t*4)=o;
}

// ---------------- GEMM: C[M,N] = A[M,K] * Bw[N,K]^T, bf16 in, fused epilogue ----
// (known-good 128x128 m97-structure; LDS XOR-chunk swizzle, global_load_lds x16,
//  XCD-aware block remap. See round-0 notes.)
// MODE 0: QKV  -> Cb[m,3072] = phi/mask per column third (extra=validf, bias=qkv_b)  [NT store]
// MODE 1: XRES -> Cf[m,N] = acc + bias + extra[m,N]   (out-proj + residual, Cf=d_out)
// MODE 2: GELU -> Cb[m,N] = bf16(gelu_exact(acc+bias))                               [NT store]
// MODE 3: ADD  -> Cf[m,N] += acc + bias               (FFN2 accumulate into x)       [NT store]
template<int MODE>
__global__ __launch_bounds__(256,2) void gemm_bt(
    const unsigned short* __restrict__ A, const unsigned short* __restrict__ Bw,
    const float* __restrict__ bias, const float* __restrict__ extra,
    float* __restrict__ Cf, unsigned short* __restrict__ Cb,
    int M, int N, int K)
{
  __shared__ __align__(16) unsigned short As[128*64];
  __shared__ __align__(16) unsigned short Bs[128*64];
  const int tid = threadIdx.x;
  const int wave = tid>>6, lane = tid&63;
  const int wm = wave>>1, wn = wave&1;          // 2x2 wave grid, 64x64 per wave
  // XCD-aware remap (grids here always have gridDim.y==256, total%8==0)
  const int f   = blockIdx.y * gridDim.x + blockIdx.x;
  const int xcd = f & 7, kk = f >> 3;
  const int nx  = kk % gridDim.x;
  const int ny  = (kk / gridDim.x) * 8 + xcd;
  const int m0 = ny*128, n0 = nx*128;
  const int lrow = lane>>3;                     // 0..7 rows within a wave-op
  const int gcol = (((lane&7) ^ lrow))*8;       // swizzled global chunk for staging

  f32x4 acc[4][4];
  #pragma unroll
  for(int i=0;i<4;i++)
    #pragma unroll
    for(int j=0;j<4;j++) acc[i][j]=(f32x4)(0.f);

  const int ar = wm*64 + (lane&15);             // A frag row in tile
  const int br = wn*64 + (lane&15);             // B frag row in tile
  const int kc = lane>>4;                       // k chunk sub-index (0..3)
  const int xorv = lane&7;                      // row&7 == lane&7 for all frags

  for(int kt=0; kt<K; kt+=64){
    #pragma unroll
    for(int it=0; it<4; it++){
      int wo = wave*4+it;                       // wave-op 0..15, 8 rows each
      int r  = wo*8 + lrow;
      async16(A  + (size_t)(m0+r)*K + kt + gcol, (void*)&As[wo*512]);
      async16(Bw + (size_t)(n0+r)*K + kt + gcol, (void*)&Bs[wo*512]);
    }
    __syncthreads();   // compiler drains vmcnt before s_barrier -> tiles ready
    #pragma unroll
    for(int ks=0; ks<2; ks++){
      const int ch = ((ks*4 + kc) ^ xorv)*8;    // swizzled LDS chunk offset
      short8 a[4], b[4];
      #pragma unroll
      for(int i=0;i<4;i++){
        a[i]=*(const short8*)&As[(ar+i*16)*64 + ch];
        b[i]=*(const short8*)&Bs[(br+i*16)*64 + ch];
      }
      #pragma unroll
      for(int i=0;i<4;i++)
        #pragma unroll
        for(int j=0;j<4;j++)
          acc[i][j]=__builtin_amdgcn_mfma_f32_16x16x32_bf16(a[i],b[j],acc[i][j],0,0,0);
    }
    __syncthreads();
  }
  // epilogue: C/D layout col=lane&15, row=(lane>>4)*4+reg
  const int rbase = m0 + wm*64 + (lane>>4)*4;
  const int cbase = n0 + wn*64 + (lane&15);
  #pragma unroll
  for(int mi=0;mi<4;mi++){
    #pragma unroll
    for(int i=0;i<4;i++){
      int m = rbase + mi*16 + i;
      #pragma unroll
      for(int ni=0;ni<4;ni++){
        int n = cbase + ni*16;
        float v = acc[mi][ni][i] + bias[n];
        if(MODE==0){
          float valid = extra[m];
          int part = n>>10;                      // 0=q,1=k,2=v
          float p = (v>0.f)? (v+1.f) : __expf(v);// phi = elu+1
          float r = (part==0)? p : (part==1? p*valid : v*valid);
          nt_store_us(f2b(r), &Cb[(size_t)m*N + n]);
        } else if(MODE==1){
          size_t off=(size_t)m*N+n;
          Cf[off] = v + extra[off];
        } else if(MODE==2){
          float gl = 0.5f*v*(1.f+erff(v*0.70710678118654752f));
          nt_store_us(f2b(gl), &Cb[(size_t)m*N+n]);
        } else {
          size_t off=(size_t)m*N+n;
          nt_store_f(Cf[off] + v, &Cf[off]);
        }
      }
    }
  }
}

// ---------------- kv = phi(k)^T v, z = sum phi(k), partial over 256-row chunks ----
// 64-row LDS tiles (32KB): 4 stage iters x 64-row inner loop -> 8 syncs/block
__global__ __launch_bounds__(256) void kvz_partial_kernel(
    const unsigned short* __restrict__ qkv, float* __restrict__ kvp, float* __restrict__ zp)
{
  const int chunk = blockIdx.x;   // 0..15 (256 rows each)
  const int bh = blockIdx.y;      // 0..127
  const int b = bh>>4, h = bh&15;
  const int t = threadIdx.x;
  __shared__ float kfs[64][64];
  __shared__ float vs[64][64];
  float acc[4][4]={{0}}; float zacc[4]={0};
  const int td=t&15, te=t>>4;
  const int d0=td*4, e0=te*4;
  const int lr=t>>4, lc=(t&15)*4;
  for(int s=0;s<4;s++){
    __syncthreads();
    #pragma unroll
    for(int rr=0; rr<4; rr++){
      int row = rr*16 + lr;
      size_t m  = (size_t)(b*SEQ + chunk*256 + s*64 + row);
      size_t rb = m*3072 + (size_t)h*64;
      ushort4 k4 = *(const ushort4*)(qkv + rb + 1024 + lc);
      ushort4 v4 = *(const ushort4*)(qkv + rb + 2048 + lc);
      kfs[row][lc]=b2f(k4.x); kfs[row][lc+1]=b2f(k4.y); kfs[row][lc+2]=b2f(k4.z); kfs[row][lc+3]=b2f(k4.w);
      vs [row][lc]=b2f(v4.x); vs [row][lc+1]=b2f(v4.y); vs [row][lc+2]=b2f(v4.z); vs [row][lc+3]=b2f(v4.w);
    }
    __syncthreads();
    #pragma unroll 8
    for(int n=0;n<64;n++){
      float4 kq=*(const float4*)&kfs[n][d0];
      float4 vv=*(const float4*)&vs[n][e0];
      float kqa[4]={kq.x,kq.y,kq.z,kq.w};
      float vva[4]={vv.x,vv.y,vv.z,vv.w};
      #pragma unroll
      for(int i=0;i<4;i++)
        #pragma unroll
        for(int j=0;j<4;j++) acc[i][j]+=kqa[i]*vva[j];
      if(te==0){ zacc[0]+=kq.x; zacc[1]+=kq.y; zacc[2]+=kq.z; zacc[3]+=kq.w; }
    }
  }
  const int pidx = bh*16 + chunk;
  float* kvd = kvp + (size_t)pidx*4096;
  #pragma unroll
  for(int i=0;i<4;i++){
    float4 o={acc[i][0],acc[i][1],acc[i][2],acc[i][3]};
    *(float4*)(kvd + (d0+i)*64 + e0)=o;
  }
  if(te==0){
    float4 o={zacc[0],zacc[1],zacc[2],zacc[3]};
    *(float4*)(zp + (size_t)pidx*64 + d0)=o;
  }
}

__global__ void kvz_reduce_kernel(const float* __restrict__ kvp, const float* __restrict__ zp,
                                  float* __restrict__ kv, float* __restrict__ z){
  int bh = blockIdx.x, t = threadIdx.x;
  for(int j=t; j<4096; j+=256){
    float s=0;
    for(int c=0;c<16;c++) s += kvp[((size_t)bh*16+c)*4096 + j];
    kv[(size_t)bh*4096 + j] = s;
  }
  if(t<64){
    float s=0;
    for(int c=0;c<16;c++) s += zp[((size_t)bh*16+c)*64 + t];
    z[bh*64+t]=s;
  }
}

// ---------------- y = (qf @ kv) / max(qf . z, eps) -> bf16 [MTOK, 1024] ----------
__global__ __launch_bounds__(256) void y_kernel(
    const unsigned short* __restrict__ qkv, const float* __restrict__ kv,
    const float* __restrict__ z, unsigned short* __restrict__ ybuf)
{
  const int nch = blockIdx.x;   // 0..63 (64 rows each)
  const int bh  = blockIdx.y;   // 0..127
  const int b = bh>>4, h = bh&15;
  const int t = threadIdx.x;
  __shared__ float kvs[64][64];
  __shared__ float qfs[64][68];  // padded: breaks 4-way bank conflict on column reads
  __shared__ float zs[64];
  // stage kv (fp32) and z
  for(int j=t*4; j<4096; j+=1024){
    float4 vv=*(const float4*)(kv+(size_t)bh*4096+j);
    ((float*)kvs)[j]=vv.x; ((float*)kvs)[j+1]=vv.y; ((float*)kvs)[j+2]=vv.z; ((float*)kvs)[j+3]=vv.w;
  }
  if(t<64) zs[t]=z[bh*64+t];
  // stage qf tile (64 rows x 64 d)
  for(int s=0;s<4;s++){
    int row=s*16+(t>>4), col=(t&15)*4;
    size_t m=(size_t)(b*SEQ+nch*64+row);
    ushort4 q4=*(const ushort4*)(qkv+m*3072+(size_t)h*64+col);
    qfs[row][col]=b2f(q4.x); qfs[row][col+1]=b2f(q4.y); qfs[row][col+2]=b2f(q4.z); qfs[row][col+3]=b2f(q4.w);
  }
  __syncthreads();
  const int tn=t>>4, te=t&15;
  const int nr0=tn*4, e0=te*4;
  float acc[4][4]={{0}}; float den[4]={0};
  #pragma unroll 4
  for(int d=0;d<64;d++){
    float4 kv4=*(const float4*)&kvs[d][e0];
    float zd=zs[d];
    #pragma unroll
    for(int i=0;i<4;i++){
      float q=qfs[nr0+i][d];
      acc[i][0]+=q*kv4.x; acc[i][1]+=q*kv4.y; acc[i][2]+=q*kv4.z; acc[i][3]+=q*kv4.w;
      den[i]+=q*zd;
    }
  }
  #pragma unroll
  for(int i=0;i<4;i++){
    float inv=1.f/fmaxf(den[i],1e-6f);
    ushort4 o;
    o.x=f2b(acc[i][0]*inv); o.y=f2b(acc[i][1]*inv); o.z=f2b(acc[i][2]*inv); o.w=f2b(acc[i][3]*inv);
    size_t m=(size_t)(b*SEQ+nch*64+nr0+i);
    *(ushort4*)(ybuf+m*1024+(size_t)h*64+e0)=o;
  }
}

extern "C" void kernel_launch(void* const* d_in, const int* in_sizes, int n_in,
                              void* d_out, int out_size, void* d_ws, size_t ws_size,
                              hipStream_t stream)
{
  const float* src   = (const float*)d_in[0];
  const void*  mask  = d_in[1];
  const float* qkv_w = (const float*)d_in[2];
  const float* qkv_b = (const float*)d_in[3];
  const float* out_w = (const float*)d_in[4];
  const float* out_b = (const float*)d_in[5];
  const float* w1    = (const float*)d_in[6];
  const float* b1    = (const float*)d_in[7];
  const float* w2    = (const float*)d_in[8];
  const float* b2    = (const float*)d_in[9];
  const float* ln1g  = (const float*)d_in[10];
  const float* ln1b  = (const float*)d_in[11];
  const float* ln2g  = (const float*)d_in[12];
  const float* ln2b  = (const float*)d_in[13];
  float* out = (float*)d_out;
  char* ws = (char*)d_ws;

  // workspace layout (~346 MiB total)
  size_t o = 0;
  int* flag = (int*)(ws);                         o += 256;
  float* validf = (float*)(ws+o);                 o += (size_t)MTOK*4;
  unsigned short* wqb = (unsigned short*)(ws+o);  o += (size_t)3072*1024*2;
  unsigned short* wob = (unsigned short*)(ws+o);  o += (size_t)1024*1024*2;
  unsigned short* w1b = (unsigned short*)(ws+o);  o += (size_t)4096*1024*2;
  unsigned short* w2b = (unsigned short*)(ws+o);  o += (size_t)1024*4096*2;
  unsigned short* bufA = (unsigned short*)(ws+o); o += (size_t)MTOK*1024*2;       // ln1 -> y -> ln2
  char* R = ws+o;                                 o += (size_t)MTOK*4096*2;       // qkv (201MB) then h (268MB)
  unsigned short* qkvbuf = (unsigned short*)R;
  float* kvp = (float*)(R + (size_t)MTOK*3072*2);                                  // fits in R tail
  float* zp  = (float*)(R + (size_t)MTOK*3072*2 + (size_t)2048*4096*4);
  unsigned short* hbuf = (unsigned short*)R;
  float* kv = (float*)(ws+o);                     o += (size_t)128*4096*4;
  float* zv = (float*)(ws+o);                     o += (size_t)128*64*4;

  detect_mask_kernel<<<1,256,0,stream>>>((const unsigned int*)mask, flag);
  decode_mask_kernel<<<MTOK/256,256,0,stream>>>(mask, flag, validf);
  cast_all_kernel<<<12288,256,0,stream>>>(qkv_w, out_w, w1, w2, wqb, wob, w1b, w2b);

  ln_kernel<<<MTOK,256,0,stream>>>(src, ln1g, ln1b, bufA);
  gemm_bt<0><<<dim3(3072/128, MTOK/128),256,0,stream>>>(bufA, wqb, qkv_b, validf, nullptr, qkvbuf, MTOK,3072,1024);
  kvz_partial_kernel<<<dim3(16,128),256,0,stream>>>(qkvbuf, kvp, zp);
  kvz_reduce_kernel<<<128,256,0,stream>>>(kvp, zp, kv, zv);
  y_kernel<<<dim3(64,128),256,0,stream>>>(qkvbuf, kv, zv, bufA);
  gemm_bt<1><<<dim3(1024/128, MTOK/128),256,0,stream>>>(bufA, wob, out_b, src, out, nullptr, MTOK,1024,1024);
  ln_kernel<<<MTOK,256,0,stream>>>(out, ln2g, ln2b, bufA);
  gemm_bt<2><<<dim3(4096/128, MTOK/128),256,0,stream>>>(bufA, w1b, b1, nullptr, nullptr, hbuf, MTOK,4096,1024);
  gemm_bt<3><<<dim3(1024/128, MTOK/128),256,0,stream>>>(hbuf, w2b, b2, nullptr, out, nullptr, MTOK,1024,4096);
}

// Round 4
// 1359.533 us; speedup vs baseline: 1.1479x; 1.0793x over previous
//
#include <hip/hip_runtime.h>
#include <cmath>
#include <cstdint>

// Problem constants (B=8, N=4096, C=1024, H=16, D=64, FF=4096)
#define MTOK 32768   // B*N tokens
#define CDIM 1024
#define SEQ  4096
#define NHEAD 16
#define HDIM 64
#define FFDIM 4096

typedef __attribute__((ext_vector_type(8))) short short8;   // 8 bf16 (4 VGPRs)
typedef __attribute__((ext_vector_type(4))) float f32x4;

static __device__ __forceinline__ float b2f(unsigned short u){
  union { unsigned int i; float f; } c; c.i = ((unsigned int)u)<<16; return c.f;
}
static __device__ __forceinline__ unsigned short f2b(float f){
  union { float f; unsigned int i; } c; c.f = f;
  return (unsigned short)((c.i + 0x7fffu + ((c.i>>16)&1u)) >> 16);  // RNE
}
// async global->LDS, 16B/lane; LDS dest = wave-uniform base + lane*16
static __device__ __forceinline__ void async16(const void* g, void* l){
  __builtin_amdgcn_global_load_lds((const __attribute__((address_space(1))) void*)g,
                                   (__attribute__((address_space(3))) void*)l, 16, 0, 0);
}

// ---------------- mask dtype detection + decode ----------------
__global__ void detect_mask_kernel(const unsigned int* __restrict__ m, int* __restrict__ flag){
  __shared__ int any;
  if(threadIdx.x==0) any=0;
  __syncthreads();
  int loc=0;
  for(int i=threadIdx.x;i<8192;i+=256) if(m[i]>1u) loc=1;
  if(loc) atomicOr(&any,1);
  __syncthreads();
  if(threadIdx.x==0) *flag=any;
}
__global__ void decode_mask_kernel(const void* __restrict__ m, const int* __restrict__ flag,
                                   float* __restrict__ validf){
  int i = blockIdx.x*256 + threadIdx.x;   // grid covers MTOK exactly
  int pad = (*flag) ? (int)((const unsigned char*)m)[i] : ((const int*)m)[i];
  validf[i] = pad ? 0.f : 1.f;
}

// ---------------- fp32 -> bf16 cast, all four weights in one launch ----------------
__global__ void cast_all_kernel(const float* __restrict__ a, const float* __restrict__ b,
                                const float* __restrict__ c, const float* __restrict__ d,
                                unsigned short* __restrict__ oa, unsigned short* __restrict__ ob,
                                unsigned short* __restrict__ oc, unsigned short* __restrict__ od){
  long i = ((long)blockIdx.x*256 + threadIdx.x)*4;   // total 12582912 elems -> 12288 blocks
  const float* x; unsigned short* y; long off;
  if(i < 3145728){ x=a; y=oa; off=i; }
  else if(i < 4194304){ x=b; y=ob; off=i-3145728; }
  else if(i < 8388608){ x=c; y=oc; off=i-4194304; }
  else { x=d; y=od; off=i-8388608; }
  float4 v = *(const float4*)(x+off);
  ushort4 o; o.x=f2b(v.x); o.y=f2b(v.y); o.z=f2b(v.z); o.w=f2b(v.w);
  *(ushort4*)(y+off)=o;
}

// ---------------- LayerNorm (C=1024) -> bf16 ----------------
__global__ __launch_bounds__(256) void ln_kernel(const float* __restrict__ x,
    const float* __restrict__ g, const float* __restrict__ bt, unsigned short* __restrict__ out){
  int row = blockIdx.x, t = threadIdx.x;
  const float* xr = x + (size_t)row*CDIM;
  float4 v = *(const float4*)(xr + t*4);
  float s1 = v.x+v.y+v.z+v.w;
  float s2 = v.x*v.x+v.y*v.y+v.z*v.z+v.w*v.w;
  #pragma unroll
  for(int off=32; off>0; off>>=1){ s1+=__shfl_down(s1,off); s2+=__shfl_down(s2,off); }
  __shared__ float a1[4], a2[4];
  __shared__ float mu_s, rs_s;
  if((t&63)==0){ a1[t>>6]=s1; a2[t>>6]=s2; }
  __syncthreads();
  if(t==0){
    float u1=a1[0]+a1[1]+a1[2]+a1[3], u2=a2[0]+a2[1]+a2[2]+a2[3];
    float mu=u1*(1.f/CDIM);
    mu_s=mu; rs_s=rsqrtf(u2*(1.f/CDIM)-mu*mu+1e-5f);
  }
  __syncthreads();
  float mu=mu_s, rs=rs_s;
  float4 gg=*(const float4*)(g+t*4), bb=*(const float4*)(bt+t*4);
  ushort4 o;
  o.x=f2b((v.x-mu)*rs*gg.x+bb.x);
  o.y=f2b((v.y-mu)*rs*gg.y+bb.y);
  o.z=f2b((v.z-mu)*rs*gg.z+bb.z);
  o.w=f2b((v.w-mu)*rs*gg.w+bb.w);
  *(ushort4*)(out+(size_t)row*CDIM+t*4)=o;
}

// ---------------- GEMM: C[M,N] = A[M,K] * Bw[N,K]^T, bf16 in, fused epilogue ----
// known-good 128x128 m97-structure; LDS XOR-chunk swizzle, global_load_lds x16.
// XCD walk: per XCD, blocks grouped into 8(ny) x 4(nx) super-tiles so the ~32
// concurrently-resident blocks touch 8 A-panels + 4 B-panels (3 MB @ K=1024)
// <= 4 MB XCD L2 (old walk: 1 A + 32 B = 8.25 MB -> B thrash, 907 MB FETCH).
// MODE 0: QKV -> q: phi(q) -> Cb[m][1024]; k: phi(k)*valid -> Kt[bh][d][pos];
//         v: v*valid -> Vt[bh][d][pos]  (K/V stored TRANSPOSED for MFMA kvz)
// MODE 1: XRES -> Cf[m,N] = acc + bias + extra[m,N]   (out-proj + residual, Cf=d_out)
// MODE 2: GELU -> Cb[m,N] = bf16(gelu_exact(acc+bias))
// MODE 3: ADD  -> Cf[m,N] += acc + bias               (FFN2 accumulate into x)
template<int MODE>
__global__ __launch_bounds__(256,2) void gemm_bt(
    const unsigned short* __restrict__ A, const unsigned short* __restrict__ Bw,
    const float* __restrict__ bias, const float* __restrict__ extra,
    float* __restrict__ Cf, unsigned short* __restrict__ Cb,
    unsigned short* __restrict__ Kt, unsigned short* __restrict__ Vt,
    int M, int N, int K)
{
  __shared__ __align__(16) unsigned short As[128*64];
  __shared__ __align__(16) unsigned short Bs[128*64];
  const int tid = threadIdx.x;
  const int wave = tid>>6, lane = tid&63;
  const int wm = wave>>1, wn = wave&1;          // 2x2 wave grid, 64x64 per wave
  // XCD-aware grouped remap (gridDim.y==256, gridDim.x%4==0, total%8==0)
  const int gx  = gridDim.x;
  const int f   = blockIdx.y * gx + blockIdx.x;
  const int xcd = f & 7;
  const int kk  = f >> 3;
  const int idx = kk & 31, g = kk >> 5;
  const int nq  = gx >> 2;
  const int gxq = g % nq, gy = g / nq;
  const int nx  = gxq*4 + (idx>>3);
  const int ny  = (gy*8 + (idx&7))*8 + xcd;
  const int m0 = ny*128, n0 = nx*128;
  const int lrow = lane>>3;                     // 0..7 rows within a wave-op
  const int gcol = (((lane&7) ^ lrow))*8;       // swizzled global chunk for staging

  f32x4 acc[4][4];
  #pragma unroll
  for(int i=0;i<4;i++)
    #pragma unroll
    for(int j=0;j<4;j++) acc[i][j]=(f32x4)(0.f);

  const int ar = wm*64 + (lane&15);             // A frag row in tile
  const int br = wn*64 + (lane&15);             // B frag row in tile
  const int kc = lane>>4;                       // k chunk sub-index (0..3)
  const int xorv = lane&7;                      // row&7 == lane&7 for all frags

  for(int kt=0; kt<K; kt+=64){
    #pragma unroll
    for(int it=0; it<4; it++){
      int wo = wave*4+it;                       // wave-op 0..15, 8 rows each
      int r  = wo*8 + lrow;
      async16(A  + (size_t)(m0+r)*K + kt + gcol, (void*)&As[wo*512]);
      async16(Bw + (size_t)(n0+r)*K + kt + gcol, (void*)&Bs[wo*512]);
    }
    __syncthreads();   // compiler drains vmcnt before s_barrier -> tiles ready
    #pragma unroll
    for(int ks=0; ks<2; ks++){
      const int ch = ((ks*4 + kc) ^ xorv)*8;    // swizzled LDS chunk offset
      short8 a[4], b[4];
      #pragma unroll
      for(int i=0;i<4;i++){
        a[i]=*(const short8*)&As[(ar+i*16)*64 + ch];
        b[i]=*(const short8*)&Bs[(br+i*16)*64 + ch];
      }
      #pragma unroll
      for(int i=0;i<4;i++)
        #pragma unroll
        for(int j=0;j<4;j++)
          acc[i][j]=__builtin_amdgcn_mfma_f32_16x16x32_bf16(a[i],b[j],acc[i][j],0,0,0);
    }
    __syncthreads();
  }
  // epilogue: C/D layout col=lane&15, row=(lane>>4)*4+reg
  const int rbase = m0 + wm*64 + (lane>>4)*4;
  const int cbase = n0 + wn*64 + (lane&15);
  if(MODE==0){
    #pragma unroll
    for(int mi=0;mi<4;mi++){
      int mrow = rbase + mi*16;
      float4 vld = *(const float4*)(extra + mrow);   // validf, mrow%4==0
      float vv[4] = {vld.x, vld.y, vld.z, vld.w};
      #pragma unroll
      for(int ni=0;ni<4;ni++){
        int n = cbase + ni*16;
        float bs = bias[n];
        int part = n>>10;                            // 0=q,1=k,2=v (tile never straddles)
        if(part==0){
          #pragma unroll
          for(int i=0;i<4;i++){
            float v = acc[mi][ni][i] + bs;
            float p = (v>0.f)? (v+1.f) : __expf(v);  // phi = elu+1
            Cb[(size_t)(mrow+i)*1024 + n] = f2b(p);  // qb[m][1024]
          }
        } else {
          int d = n & 63, hh = (n>>6) & 15;
          int bb_ = mrow >> 12, pos = mrow & 4095;   // pos%4==0 -> aligned ushort4
          unsigned short* dst = (part==1? Kt : Vt)
              + (((size_t)(bb_*16+hh)*64 + d)*SEQ + pos);
          ushort4 o;
          #pragma unroll
          for(int i=0;i<4;i++){
            float v = acc[mi][ni][i] + bs;
            float r = (part==1)? (((v>0.f)?(v+1.f):__expf(v))*vv[i]) : (v*vv[i]);
            ((unsigned short*)&o)[i] = f2b(r);
          }
          *(ushort4*)dst = o;                        // 4 consecutive seq positions
        }
      }
    }
  } else {
    #pragma unroll
    for(int mi=0;mi<4;mi++){
      #pragma unroll
      for(int i=0;i<4;i++){
        int m = rbase + mi*16 + i;
        #pragma unroll
        for(int ni=0;ni<4;ni++){
          int n = cbase + ni*16;
          float v = acc[mi][ni][i] + bias[n];
          if(MODE==1){
            size_t off=(size_t)m*N+n;
            Cf[off] = v + extra[off];
          } else if(MODE==2){
            float gl = 0.5f*v*(1.f+erff(v*0.70710678118654752f));
            Cb[(size_t)m*N+n] = f2b(gl);
          } else {
            size_t off=(size_t)m*N+n;
            Cf[off] += v;
          }
        }
      }
    }
  }
}

// ---------------- kvT[e][d] = sum_n v[n][e]*kf[n][d], z[d] = sum_n kf[n][d] ----
// MFMA over K=n. A-operand = Vt rows (e), B-operand = Kt rows (d) -- both stored
// [bh][64][4096] row-major-by-n, so this is exactly the gemm_bt fragment pattern.
// One wave per block; 32 k-slices of 128 per (b,h). z accumulated from the
// B-fragments (each lane's 8 elems are distinct n), reduced via shfl.
__global__ __launch_bounds__(64) void kvz_mfma_kernel(
    const unsigned short* __restrict__ Kt, const unsigned short* __restrict__ Vt,
    float* __restrict__ kvp, float* __restrict__ zp)
{
  __shared__ __align__(16) unsigned short Ks[2][64*64];
  __shared__ __align__(16) unsigned short Vs[2][64*64];
  const int blk = blockIdx.x;             // 0..4095
  const int bh = blk>>5, kcn = blk&31;    // k-slice of 128 n
  const int n0 = kcn*128;
  const int lane = threadIdx.x;
  const int r8 = lane>>3;
  const int gch = ((lane&7) ^ r8)*8;
  const size_t base = (size_t)bh*64*SEQ + n0 + gch;
  #pragma unroll
  for(int t=0;t<2;t++){
    #pragma unroll
    for(int wo=0;wo<8;wo++){
      int r = wo*8 + r8;
      async16(Kt + base + (size_t)r*SEQ + t*64, (void*)&Ks[t][wo*512]);
      async16(Vt + base + (size_t)r*SEQ + t*64, (void*)&Vs[t][wo*512]);
    }
  }
  asm volatile("s_waitcnt vmcnt(0)" ::: "memory");
  f32x4 acc[4][4];
  #pragma unroll
  for(int i=0;i<4;i++)
    #pragma unroll
    for(int j=0;j<4;j++) acc[i][j]=(f32x4)(0.f);
  float zacc[4]={0.f,0.f,0.f,0.f};
  const int l15 = lane&15, kc4 = lane>>4, x7 = lane&7;
  #pragma unroll
  for(int t=0;t<2;t++){
    #pragma unroll
    for(int ks=0; ks<2; ks++){
      const int ch = ((ks*4 + kc4) ^ x7)*8;
      short8 a[4], b[4];
      #pragma unroll
      for(int i=0;i<4;i++) a[i]=*(const short8*)&Vs[t][(l15+i*16)*64 + ch];
      #pragma unroll
      for(int j=0;j<4;j++) b[j]=*(const short8*)&Ks[t][(l15+j*16)*64 + ch];
      #pragma unroll
      for(int j=0;j<4;j++)
        #pragma unroll
        for(int e8=0;e8<8;e8++) zacc[j] += b2f((unsigned short)b[j][e8]);
      #pragma unroll
      for(int i=0;i<4;i++)
        #pragma unroll
        for(int j=0;j<4;j++)
          acc[i][j]=__builtin_amdgcn_mfma_f32_16x16x32_bf16(a[i],b[j],acc[i][j],0,0,0);
    }
  }
  // z: lanes l, l+16, l+32, l+48 hold disjoint n-chunks of d = j*16+l15
  #pragma unroll
  for(int j=0;j<4;j++){
    float v = zacc[j];
    v += __shfl_down(v, 32);
    v += __shfl_down(v, 16);
    if(lane<16) zp[(size_t)blk*64 + j*16 + lane] = v;
  }
  float* kvd = kvp + (size_t)blk*4096;
  #pragma unroll
  for(int i=0;i<4;i++)
    #pragma unroll
    for(int j=0;j<4;j++)
      #pragma unroll
      for(int r=0;r<4;r++)
        kvd[(i*16 + kc4*4 + r)*64 + j*16 + l15] = acc[i][j][r];
}

// reduce 32 partials -> kvtb[bh][80][64] bf16: rows 0..63 kvT, row 64 = z, 65..79 = 0
__global__ void kvz_reduce_kernel(const float* __restrict__ kvp, const float* __restrict__ zp,
                                  unsigned short* __restrict__ kvtb){
  int bh = blockIdx.x, t = threadIdx.x;
  for(int idx=t; idx<5120; idx+=256){
    int e = idx>>6, d = idx&63;
    float s = 0.f;
    if(e < 64){
      for(int c=0;c<32;c++) s += kvp[((size_t)bh*32+c)*4096 + e*64 + d];
    } else if(e == 64){
      for(int c=0;c<32;c++) s += zp[((size_t)bh*32+c)*64 + d];
    }
    kvtb[(size_t)bh*5120 + idx] = f2b(s);
  }
}

// ---------------- y[m][e] = (qf @ kvT^T)/max(qf.z,eps) via MFMA, K=64 ----------
// B-tile = kvtb[bh][80][64]: rows 0..63 -> y cols, row 64 -> denominator col.
__global__ __launch_bounds__(256) void y_gemm_kernel(
    const unsigned short* __restrict__ qb, const unsigned short* __restrict__ kvtb,
    unsigned short* __restrict__ ybuf)
{
  __shared__ __align__(16) unsigned short As[128*64];
  __shared__ __align__(16) unsigned short Bs[80*64];
  const int tid = threadIdx.x, lane = tid&63, wave = tid>>6;
  const int bh = blockIdx.y, b = bh>>4, h = bh&15;
  const int m0 = blockIdx.x*128;
  const int r8 = lane>>3, gch = ((lane&7)^r8)*8;
  const unsigned short* qbase = qb + ((size_t)(b*SEQ + m0))*1024 + h*64 + gch;
  #pragma unroll
  for(int it=0; it<4; it++){
    int wo = wave*4 + it, r = wo*8 + r8;
    async16(qbase + (size_t)r*1024, (void*)&As[wo*512]);
  }
  const unsigned short* kvb = kvtb + (size_t)bh*5120 + gch;
  #pragma unroll
  for(int it=0; it<3; it++){
    int wo = wave + it*4;
    if(wo < 10){ int r = wo*8 + r8; async16(kvb + r*64, (void*)&Bs[wo*512]); }
  }
  __syncthreads();
  const int l15 = lane&15, kc4 = lane>>4, x7 = lane&7;
  f32x4 acc[2][5];
  #pragma unroll
  for(int i=0;i<2;i++)
    #pragma unroll
    for(int j=0;j<5;j++) acc[i][j]=(f32x4)(0.f);
  #pragma unroll
  for(int ks=0; ks<2; ks++){
    const int ch = ((ks*4 + kc4) ^ x7)*8;
    short8 a[2], bb[5];
    #pragma unroll
    for(int i=0;i<2;i++) a[i]=*(const short8*)&As[(wave*32 + i*16 + l15)*64 + ch];
    #pragma unroll
    for(int j=0;j<5;j++) bb[j]=*(const short8*)&Bs[(j*16 + l15)*64 + ch];
    #pragma unroll
    for(int i=0;i<2;i++)
      #pragma unroll
      for(int j=0;j<5;j++)
        acc[i][j]=__builtin_amdgcn_mfma_f32_16x16x32_bf16(a[i],bb[j],acc[i][j],0,0,0);
  }
  #pragma unroll
  for(int i=0;i<2;i++){
    #pragma unroll
    for(int r=0;r<4;r++){
      float den = __shfl(acc[i][4][r], lane & 48);   // col 64 lives at l15==0
      float inv = 1.f/fmaxf(den, 1e-6f);
      size_t m = (size_t)(b*SEQ + m0 + wave*32 + i*16 + kc4*4 + r);
      #pragma unroll
      for(int j=0;j<4;j++)
        ybuf[m*1024 + h*64 + j*16 + l15] = f2b(acc[i][j][r]*inv);
    }
  }
}

extern "C" void kernel_launch(void* const* d_in, const int* in_sizes, int n_in,
                              void* d_out, int out_size, void* d_ws, size_t ws_size,
                              hipStream_t stream)
{
  const float* src   = (const float*)d_in[0];
  const void*  mask  = d_in[1];
  const float* qkv_w = (const float*)d_in[2];
  const float* qkv_b = (const float*)d_in[3];
  const float* out_w = (const float*)d_in[4];
  const float* out_b = (const float*)d_in[5];
  const float* w1    = (const float*)d_in[6];
  const float* b1    = (const float*)d_in[7];
  const float* w2    = (const float*)d_in[8];
  const float* b2    = (const float*)d_in[9];
  const float* ln1g  = (const float*)d_in[10];
  const float* ln1b  = (const float*)d_in[11];
  const float* ln2g  = (const float*)d_in[12];
  const float* ln2b  = (const float*)d_in[13];
  float* out = (float*)d_out;
  char* ws = (char*)d_ws;

  // workspace layout
  size_t o = 0;
  int* flag = (int*)(ws);                         o += 256;
  float* validf = (float*)(ws+o);                 o += (size_t)MTOK*4;
  unsigned short* wqb = (unsigned short*)(ws+o);  o += (size_t)3072*1024*2;
  unsigned short* wob = (unsigned short*)(ws+o);  o += (size_t)1024*1024*2;
  unsigned short* w1b = (unsigned short*)(ws+o);  o += (size_t)4096*1024*2;
  unsigned short* w2b = (unsigned short*)(ws+o);  o += (size_t)1024*4096*2;
  unsigned short* bufA = (unsigned short*)(ws+o); o += (size_t)MTOK*1024*2;       // ln1 -> y -> ln2
  char* R = ws+o;                                 o += (size_t)MTOK*4096*2;       // attn bufs, then h
  unsigned short* qb  = (unsigned short*)R;                                        // 67 MB phi(q) [m][1024]
  unsigned short* ktb = (unsigned short*)(R + (size_t)MTOK*1024*2);                // 67 MB K^T [bh][64][4096]
  unsigned short* vtb = (unsigned short*)(R + (size_t)MTOK*2048*2);                // 67 MB V^T
  float* kvp = (float*)(R + (size_t)MTOK*3072*2);                                  // 67 MB partials (fills R)
  unsigned short* hbuf = (unsigned short*)R;                                       // FFN h aliases R
  float* kv = (float*)(ws+o);                     o += (size_t)128*4096*4;         // (spare)
  float* zv = (float*)(ws+o);                     o += (size_t)128*64*4;
  float* zp = (float*)(ws+o);                     o += (size_t)4096*64*4;          // 1 MB z partials
  unsigned short* kvtb = (unsigned short*)(ws+o); o += (size_t)128*5120*2;         // 1.25 MB kvT+z bf16
  (void)kv; (void)zv;

  detect_mask_kernel<<<1,256,0,stream>>>((const unsigned int*)mask, flag);
  decode_mask_kernel<<<MTOK/256,256,0,stream>>>(mask, flag, validf);
  cast_all_kernel<<<12288,256,0,stream>>>(qkv_w, out_w, w1, w2, wqb, wob, w1b, w2b);

  ln_kernel<<<MTOK,256,0,stream>>>(src, ln1g, ln1b, bufA);
  gemm_bt<0><<<dim3(3072/128, MTOK/128),256,0,stream>>>(bufA, wqb, qkv_b, validf, nullptr, qb, ktb, vtb, MTOK,3072,1024);
  kvz_mfma_kernel<<<4096,64,0,stream>>>(ktb, vtb, kvp, zp);
  kvz_reduce_kernel<<<128,256,0,stream>>>(kvp, zp, kvtb);
  y_gemm_kernel<<<dim3(SEQ/128,128),256,0,stream>>>(qb, kvtb, bufA);
  gemm_bt<1><<<dim3(1024/128, MTOK/128),256,0,stream>>>(bufA, wob, out_b, src, out, nullptr, nullptr, nullptr, MTOK,1024,1024);
  ln_kernel<<<MTOK,256,0,stream>>>(out, ln2g, ln2b, bufA);
  gemm_bt<2><<<dim3(4096/128, MTOK/128),256,0,stream>>>(bufA, w1b, b1, nullptr, nullptr, hbuf, nullptr, nullptr, MTOK,4096,1024);
  gemm_bt<3><<<dim3(1024/128, MTOK/128),256,0,stream>>>(hbuf, w2b, b2, nullptr, out, nullptr, nullptr, nullptr, MTOK,1024,4096);
}

// Round 5
// 1320.480 us; speedup vs baseline: 1.1819x; 1.0296x over previous
//
#include <hip/hip_runtime.h>
#include <cmath>
#include <cstdint>

// Problem constants (B=8, N=4096, C=1024, H=16, D=64, FF=4096)
#define MTOK 32768   // B*N tokens
#define CDIM 1024
#define SEQ  4096
#define NHEAD 16
#define HDIM 64
#define FFDIM 4096

typedef __attribute__((ext_vector_type(8))) short short8;   // 8 bf16 (4 VGPRs)
typedef __attribute__((ext_vector_type(4))) float f32x4;

static __device__ __forceinline__ float b2f(unsigned short u){
  union { unsigned int i; float f; } c; c.i = ((unsigned int)u)<<16; return c.f;
}
static __device__ __forceinline__ unsigned short f2b(float f){
  union { float f; unsigned int i; } c; c.f = f;
  return (unsigned short)((c.i + 0x7fffu + ((c.i>>16)&1u)) >> 16);  // RNE
}
// gelu_exact via A&S 7.1.26 erf (|eps|<=1.5e-7, far below bf16 quantum):
// ~12 VALU vs ~35 for libm erff -- the FFN1 epilogue was VALU-heavy (r3 PMC).
static __device__ __forceinline__ float fast_gelu(float v){
  float s = v*0.70710678118654752f;
  float a = fabsf(s);
  float t = 1.f/(1.f + 0.3275911f*a);
  float p = t*(0.254829592f + t*(-0.284496736f + t*(1.421413741f +
            t*(-1.453152027f + t*1.061405429f))));
  float erfa = 1.f - p*__expf(-a*a);
  float er = (s<0.f)? -erfa : erfa;
  return 0.5f*v*(1.f+er);
}
// async global->LDS, 16B/lane; LDS dest = wave-uniform base + lane*16
static __device__ __forceinline__ void async16(const void* g, void* l){
  __builtin_amdgcn_global_load_lds((const __attribute__((address_space(1))) void*)g,
                                   (__attribute__((address_space(3))) void*)l, 16, 0, 0);
}

// ---------------- mask dtype detection + decode ----------------
__global__ void detect_mask_kernel(const unsigned int* __restrict__ m, int* __restrict__ flag){
  __shared__ int any;
  if(threadIdx.x==0) any=0;
  __syncthreads();
  int loc=0;
  for(int i=threadIdx.x;i<8192;i+=256) if(m[i]>1u) loc=1;
  if(loc) atomicOr(&any,1);
  __syncthreads();
  if(threadIdx.x==0) *flag=any;
}
__global__ void decode_mask_kernel(const void* __restrict__ m, const int* __restrict__ flag,
                                   float* __restrict__ validf){
  int i = blockIdx.x*256 + threadIdx.x;   // grid covers MTOK exactly
  int pad = (*flag) ? (int)((const unsigned char*)m)[i] : ((const int*)m)[i];
  validf[i] = pad ? 0.f : 1.f;
}

// ---------------- fp32 -> bf16 cast, all four weights in one launch ----------------
__global__ void cast_all_kernel(const float* __restrict__ a, const float* __restrict__ b,
                                const float* __restrict__ c, const float* __restrict__ d,
                                unsigned short* __restrict__ oa, unsigned short* __restrict__ ob,
                                unsigned short* __restrict__ oc, unsigned short* __restrict__ od){
  long i = ((long)blockIdx.x*256 + threadIdx.x)*4;   // total 12582912 elems -> 12288 blocks
  const float* x; unsigned short* y; long off;
  if(i < 3145728){ x=a; y=oa; off=i; }
  else if(i < 4194304){ x=b; y=ob; off=i-3145728; }
  else if(i < 8388608){ x=c; y=oc; off=i-4194304; }
  else { x=d; y=od; off=i-8388608; }
  float4 v = *(const float4*)(x+off);
  ushort4 o; o.x=f2b(v.x); o.y=f2b(v.y); o.z=f2b(v.z); o.w=f2b(v.w);
  *(ushort4*)(y+off)=o;
}

// ---------------- LayerNorm (C=1024) -> bf16 ----------------
__global__ __launch_bounds__(256) void ln_kernel(const float* __restrict__ x,
    const float* __restrict__ g, const float* __restrict__ bt, unsigned short* __restrict__ out){
  int row = blockIdx.x, t = threadIdx.x;
  const float* xr = x + (size_t)row*CDIM;
  float4 v = *(const float4*)(xr + t*4);
  float s1 = v.x+v.y+v.z+v.w;
  float s2 = v.x*v.x+v.y*v.y+v.z*v.z+v.w*v.w;
  #pragma unroll
  for(int off=32; off>0; off>>=1){ s1+=__shfl_down(s1,off); s2+=__shfl_down(s2,off); }
  __shared__ float a1[4], a2[4];
  __shared__ float mu_s, rs_s;
  if((t&63)==0){ a1[t>>6]=s1; a2[t>>6]=s2; }
  __syncthreads();
  if(t==0){
    float u1=a1[0]+a1[1]+a1[2]+a1[3], u2=a2[0]+a2[1]+a2[2]+a2[3];
    float mu=u1*(1.f/CDIM);
    mu_s=mu; rs_s=rsqrtf(u2*(1.f/CDIM)-mu*mu+1e-5f);
  }
  __syncthreads();
  float mu=mu_s, rs=rs_s;
  float4 gg=*(const float4*)(g+t*4), bb=*(const float4*)(bt+t*4);
  ushort4 o;
  o.x=f2b((v.x-mu)*rs*gg.x+bb.x);
  o.y=f2b((v.y-mu)*rs*gg.y+bb.y);
  o.z=f2b((v.z-mu)*rs*gg.z+bb.z);
  o.w=f2b((v.w-mu)*rs*gg.w+bb.w);
  *(ushort4*)(out+(size_t)row*CDIM+t*4)=o;
}

// ---------------- GEMM: C[M,N] = A[M,K] * Bw[N,K]^T, bf16 in, fused epilogue ----
// known-good 128x128 m97-structure; LDS XOR-chunk swizzle, global_load_lds x16.
// XCD walk: per XCD, blocks grouped into 8(ny) x 4(nx) super-tiles so the ~32
// concurrently-resident blocks touch 8 A-panels + 4 B-panels (3 MB @ K=1024)
// <= 4 MB XCD L2 (old walk: 1 A + 32 B = 8.25 MB -> B thrash, 907 MB FETCH).
// MODE 0: QKV -> q: phi(q) -> Cb[m][1024]; k: phi(k)*valid -> Kt[bh][d][pos];
//         v: v*valid -> Vt[bh][d][pos]  (K/V stored TRANSPOSED for MFMA kvz)
// MODE 1: XRES -> Cf[m,N] = acc + bias + extra[m,N]   (out-proj + residual, Cf=d_out)
// MODE 2: GELU -> Cb[m,N] = bf16(gelu_exact(acc+bias))
// MODE 3: ADD  -> Cf[m,N] += acc + bias               (FFN2 accumulate into x)
template<int MODE>
__global__ __launch_bounds__(256,2) void gemm_bt(
    const unsigned short* __restrict__ A, const unsigned short* __restrict__ Bw,
    const float* __restrict__ bias, const float* __restrict__ extra,
    float* __restrict__ Cf, unsigned short* __restrict__ Cb,
    unsigned short* __restrict__ Kt, unsigned short* __restrict__ Vt,
    int M, int N, int K)
{
  __shared__ __align__(16) unsigned short As[128*64];
  __shared__ __align__(16) unsigned short Bs[128*64];
  const int tid = threadIdx.x;
  const int wave = tid>>6, lane = tid&63;
  const int wm = wave>>1, wn = wave&1;          // 2x2 wave grid, 64x64 per wave
  // XCD-aware grouped remap (gridDim.y==256, gridDim.x%4==0, total%8==0)
  const int gx  = gridDim.x;
  const int f   = blockIdx.y * gx + blockIdx.x;
  const int xcd = f & 7;
  const int kk  = f >> 3;
  const int idx = kk & 31, g = kk >> 5;
  const int nq  = gx >> 2;
  const int gxq = g % nq, gy = g / nq;
  const int nx  = gxq*4 + (idx>>3);
  const int ny  = (gy*8 + (idx&7))*8 + xcd;
  const int m0 = ny*128, n0 = nx*128;
  const int lrow = lane>>3;                     // 0..7 rows within a wave-op
  const int gcol = (((lane&7) ^ lrow))*8;       // swizzled global chunk for staging

  f32x4 acc[4][4];
  #pragma unroll
  for(int i=0;i<4;i++)
    #pragma unroll
    for(int j=0;j<4;j++) acc[i][j]=(f32x4)(0.f);

  const int ar = wm*64 + (lane&15);             // A frag row in tile
  const int br = wn*64 + (lane&15);             // B frag row in tile
  const int kc = lane>>4;                       // k chunk sub-index (0..3)
  const int xorv = lane&7;                      // row&7 == lane&7 for all frags

  for(int kt=0; kt<K; kt+=64){
    #pragma unroll
    for(int it=0; it<4; it++){
      int wo = wave*4+it;                       // wave-op 0..15, 8 rows each
      int r  = wo*8 + lrow;
      async16(A  + (size_t)(m0+r)*K + kt + gcol, (void*)&As[wo*512]);
      async16(Bw + (size_t)(n0+r)*K + kt + gcol, (void*)&Bs[wo*512]);
    }
    __syncthreads();   // compiler drains vmcnt before s_barrier -> tiles ready
    #pragma unroll
    for(int ks=0; ks<2; ks++){
      const int ch = ((ks*4 + kc) ^ xorv)*8;    // swizzled LDS chunk offset
      short8 a[4], b[4];
      #pragma unroll
      for(int i=0;i<4;i++){
        a[i]=*(const short8*)&As[(ar+i*16)*64 + ch];
        b[i]=*(const short8*)&Bs[(br+i*16)*64 + ch];
      }
      #pragma unroll
      for(int i=0;i<4;i++)
        #pragma unroll
        for(int j=0;j<4;j++)
          acc[i][j]=__builtin_amdgcn_mfma_f32_16x16x32_bf16(a[i],b[j],acc[i][j],0,0,0);
    }
    __syncthreads();
  }
  // epilogue: C/D layout col=lane&15, row=(lane>>4)*4+reg
  const int rbase = m0 + wm*64 + (lane>>4)*4;
  const int cbase = n0 + wn*64 + (lane&15);
  if(MODE==0){
    #pragma unroll
    for(int mi=0;mi<4;mi++){
      int mrow = rbase + mi*16;
      float4 vld = *(const float4*)(extra + mrow);   // validf, mrow%4==0
      float vv[4] = {vld.x, vld.y, vld.z, vld.w};
      #pragma unroll
      for(int ni=0;ni<4;ni++){
        int n = cbase + ni*16;
        float bs = bias[n];
        int part = n>>10;                            // 0=q,1=k,2=v (tile never straddles)
        if(part==0){
          #pragma unroll
          for(int i=0;i<4;i++){
            float v = acc[mi][ni][i] + bs;
            float p = (v>0.f)? (v+1.f) : __expf(v);  // phi = elu+1
            Cb[(size_t)(mrow+i)*1024 + n] = f2b(p);  // qb[m][1024]
          }
        } else {
          int d = n & 63, hh = (n>>6) & 15;
          int bb_ = mrow >> 12, pos = mrow & 4095;   // pos%4==0 -> aligned ushort4
          unsigned short* dst = (part==1? Kt : Vt)
              + (((size_t)(bb_*16+hh)*64 + d)*SEQ + pos);
          ushort4 o;
          #pragma unroll
          for(int i=0;i<4;i++){
            float v = acc[mi][ni][i] + bs;
            float r = (part==1)? (((v>0.f)?(v+1.f):__expf(v))*vv[i]) : (v*vv[i]);
            ((unsigned short*)&o)[i] = f2b(r);
          }
          *(ushort4*)dst = o;                        // 4 consecutive seq positions
        }
      }
    }
  } else {
    #pragma unroll
    for(int mi=0;mi<4;mi++){
      #pragma unroll
      for(int i=0;i<4;i++){
        int m = rbase + mi*16 + i;
        #pragma unroll
        for(int ni=0;ni<4;ni++){
          int n = cbase + ni*16;
          float v = acc[mi][ni][i] + bias[n];
          if(MODE==1){
            size_t off=(size_t)m*N+n;
            Cf[off] = v + extra[off];
          } else if(MODE==2){
            Cb[(size_t)m*N+n] = f2b(fast_gelu(v));
          } else {
            size_t off=(size_t)m*N+n;
            Cf[off] += v;
          }
        }
      }
    }
  }
}

// ---------------- kvT[e][d] = sum_n v[n][e]*kf[n][d], z[d] = sum_n kf[n][d] ----
// MFMA over K=n. A-operand = Vt rows (e), B-operand = Kt rows (d) -- both stored
// [bh][64][4096] row-major-by-n == exactly the gemm_bt fragment pattern.
// One wave per block; 16 n-slices of 256 per (b,h), 2 serial rounds of 2x64-n
// chunks (32KB LDS). Single-wave block: no barriers, but lgkmcnt(0) before
// round 2's stage (LDS-DMA writes are NOT ordered vs pending ds_reads).
__global__ __launch_bounds__(64) void kvz_mfma_kernel(
    const unsigned short* __restrict__ Kt, const unsigned short* __restrict__ Vt,
    float* __restrict__ kvp, float* __restrict__ zp)
{
  __shared__ __align__(16) unsigned short Ks[2][64*64];
  __shared__ __align__(16) unsigned short Vs[2][64*64];
  const int blk = blockIdx.x;             // 0..2047
  const int bh = blk>>4, kcn = blk&15;    // n-slice of 256
  const int n0 = kcn*256;
  const int lane = threadIdx.x;
  const int r8 = lane>>3;
  const int gch = ((lane&7) ^ r8)*8;
  const size_t base = (size_t)bh*64*SEQ + n0 + gch;
  f32x4 acc[4][4];
  #pragma unroll
  for(int i=0;i<4;i++)
    #pragma unroll
    for(int j=0;j<4;j++) acc[i][j]=(f32x4)(0.f);
  float zacc[4]={0.f,0.f,0.f,0.f};
  const int l15 = lane&15, kc4 = lane>>4, x7 = lane&7;
  for(int rr=0; rr<2; rr++){
    if(rr) asm volatile("s_waitcnt lgkmcnt(0)" ::: "memory");  // ds_reads done before DMA overwrite
    #pragma unroll
    for(int t=0;t<2;t++){
      int cc = rr*2 + t;
      #pragma unroll
      for(int wo=0;wo<8;wo++){
        int r = wo*8 + r8;
        async16(Kt + base + (size_t)r*SEQ + cc*64, (void*)&Ks[t][wo*512]);
        async16(Vt + base + (size_t)r*SEQ + cc*64, (void*)&Vs[t][wo*512]);
      }
    }
    asm volatile("s_waitcnt vmcnt(0)" ::: "memory");
    #pragma unroll
    for(int t=0;t<2;t++){
      #pragma unroll
      for(int ks=0; ks<2; ks++){
        const int ch = ((ks*4 + kc4) ^ x7)*8;
        short8 a[4], b[4];
        #pragma unroll
        for(int i=0;i<4;i++) a[i]=*(const short8*)&Vs[t][(l15+i*16)*64 + ch];
        #pragma unroll
        for(int j=0;j<4;j++) b[j]=*(const short8*)&Ks[t][(l15+j*16)*64 + ch];
        #pragma unroll
        for(int j=0;j<4;j++)
          #pragma unroll
          for(int e8=0;e8<8;e8++) zacc[j] += b2f((unsigned short)b[j][e8]);
        #pragma unroll
        for(int i=0;i<4;i++)
          #pragma unroll
          for(int j=0;j<4;j++)
            acc[i][j]=__builtin_amdgcn_mfma_f32_16x16x32_bf16(a[i],b[j],acc[i][j],0,0,0);
      }
    }
  }
  // z: lanes l, l+16, l+32, l+48 hold disjoint n-chunks of d = j*16+l15
  #pragma unroll
  for(int j=0;j<4;j++){
    float v = zacc[j];
    v += __shfl_down(v, 32);
    v += __shfl_down(v, 16);
    if(lane<16) zp[(size_t)blk*64 + j*16 + lane] = v;
  }
  float* kvd = kvp + (size_t)blk*4096;
  #pragma unroll
  for(int i=0;i<4;i++)
    #pragma unroll
    for(int j=0;j<4;j++)
      #pragma unroll
      for(int r=0;r<4;r++)
        kvd[(i*16 + kc4*4 + r)*64 + j*16 + l15] = acc[i][j][r];
}

// reduce 16 partials -> kvtb[bh][80][64] bf16: rows 0..63 kvT, row 64 = z, 65..79 = 0
__global__ void kvz_reduce_kernel(const float* __restrict__ kvp, const float* __restrict__ zp,
                                  unsigned short* __restrict__ kvtb){
  int bh = blockIdx.x, t = threadIdx.x;
  for(int idx=t; idx<5120; idx+=256){
    int e = idx>>6, d = idx&63;
    float s = 0.f;
    if(e < 64){
      for(int c=0;c<16;c++) s += kvp[((size_t)bh*16+c)*4096 + e*64 + d];
    } else if(e == 64){
      for(int c=0;c<16;c++) s += zp[((size_t)bh*16+c)*64 + d];
    }
    kvtb[(size_t)bh*5120 + idx] = f2b(s);
  }
}

// ---------------- y[m][e] = (qf @ kvT^T)/max(qf.z,eps) via MFMA, K=64 ----------
// B-tile = kvtb[bh][80][64]: rows 0..63 -> y cols, row 64 -> denominator col.
__global__ __launch_bounds__(256) void y_gemm_kernel(
    const unsigned short* __restrict__ qb, const unsigned short* __restrict__ kvtb,
    unsigned short* __restrict__ ybuf)
{
  __shared__ __align__(16) unsigned short As[128*64];
  __shared__ __align__(16) unsigned short Bs[80*64];
  const int tid = threadIdx.x, lane = tid&63, wave = tid>>6;
  const int bh = blockIdx.y, b = bh>>4, h = bh&15;
  const int m0 = blockIdx.x*128;
  const int r8 = lane>>3, gch = ((lane&7)^r8)*8;
  const unsigned short* qbase = qb + ((size_t)(b*SEQ + m0))*1024 + h*64 + gch;
  #pragma unroll
  for(int it=0; it<4; it++){
    int wo = wave*4 + it, r = wo*8 + r8;
    async16(qbase + (size_t)r*1024, (void*)&As[wo*512]);
  }
  const unsigned short* kvb = kvtb + (size_t)bh*5120 + gch;
  #pragma unroll
  for(int it=0; it<3; it++){
    int wo = wave + it*4;
    if(wo < 10){ int r = wo*8 + r8; async16(kvb + r*64, (void*)&Bs[wo*512]); }
  }
  __syncthreads();
  const int l15 = lane&15, kc4 = lane>>4, x7 = lane&7;
  f32x4 acc[2][5];
  #pragma unroll
  for(int i=0;i<2;i++)
    #pragma unroll
    for(int j=0;j<5;j++) acc[i][j]=(f32x4)(0.f);
  #pragma unroll
  for(int ks=0; ks<2; ks++){
    const int ch = ((ks*4 + kc4) ^ x7)*8;
    short8 a[2], bb[5];
    #pragma unroll
    for(int i=0;i<2;i++) a[i]=*(const short8*)&As[(wave*32 + i*16 + l15)*64 + ch];
    #pragma unroll
    for(int j=0;j<5;j++) bb[j]=*(const short8*)&Bs[(j*16 + l15)*64 + ch];
    #pragma unroll
    for(int i=0;i<2;i++)
      #pragma unroll
      for(int j=0;j<5;j++)
        acc[i][j]=__builtin_amdgcn_mfma_f32_16x16x32_bf16(a[i],bb[j],acc[i][j],0,0,0);
  }
  #pragma unroll
  for(int i=0;i<2;i++){
    #pragma unroll
    for(int r=0;r<4;r++){
      float den = __shfl(acc[i][4][r], lane & 48);   // col 64 lives at l15==0
      float inv = 1.f/fmaxf(den, 1e-6f);
      size_t m = (size_t)(b*SEQ + m0 + wave*32 + i*16 + kc4*4 + r);
      #pragma unroll
      for(int j=0;j<4;j++)
        ybuf[m*1024 + h*64 + j*16 + l15] = f2b(acc[i][j][r]*inv);
    }
  }
}

extern "C" void kernel_launch(void* const* d_in, const int* in_sizes, int n_in,
                              void* d_out, int out_size, void* d_ws, size_t ws_size,
                              hipStream_t stream)
{
  const float* src   = (const float*)d_in[0];
  const void*  mask  = d_in[1];
  const float* qkv_w = (const float*)d_in[2];
  const float* qkv_b = (const float*)d_in[3];
  const float* out_w = (const float*)d_in[4];
  const float* out_b = (const float*)d_in[5];
  const float* w1    = (const float*)d_in[6];
  const float* b1    = (const float*)d_in[7];
  const float* w2    = (const float*)d_in[8];
  const float* b2    = (const float*)d_in[9];
  const float* ln1g  = (const float*)d_in[10];
  const float* ln1b  = (const float*)d_in[11];
  const float* ln2g  = (const float*)d_in[12];
  const float* ln2b  = (const float*)d_in[13];
  float* out = (float*)d_out;
  char* ws = (char*)d_ws;

  // workspace layout
  size_t o = 0;
  int* flag = (int*)(ws);                         o += 256;
  float* validf = (float*)(ws+o);                 o += (size_t)MTOK*4;
  unsigned short* wqb = (unsigned short*)(ws+o);  o += (size_t)3072*1024*2;
  unsigned short* wob = (unsigned short*)(ws+o);  o += (size_t)1024*1024*2;
  unsigned short* w1b = (unsigned short*)(ws+o);  o += (size_t)4096*1024*2;
  unsigned short* w2b = (unsigned short*)(ws+o);  o += (size_t)1024*4096*2;
  unsigned short* bufA = (unsigned short*)(ws+o); o += (size_t)MTOK*1024*2;       // ln1 -> y -> ln2
  char* R = ws+o;                                 o += (size_t)MTOK*4096*2;       // attn bufs, then h
  unsigned short* qb  = (unsigned short*)R;                                        // 67 MB phi(q) [m][1024]
  unsigned short* ktb = (unsigned short*)(R + (size_t)MTOK*1024*2);                // 67 MB K^T [bh][64][4096]
  unsigned short* vtb = (unsigned short*)(R + (size_t)MTOK*2048*2);                // 67 MB V^T
  float* kvp = (float*)(R + (size_t)MTOK*3072*2);                                  // 33.5 MB partials (fits R tail)
  unsigned short* hbuf = (unsigned short*)R;                                       // FFN h aliases R
  float* zp = (float*)(ws+o);                     o += (size_t)2048*64*4;          // 0.5 MB z partials
  unsigned short* kvtb = (unsigned short*)(ws+o); o += (size_t)128*5120*2;         // 1.25 MB kvT+z bf16

  detect_mask_kernel<<<1,256,0,stream>>>((const unsigned int*)mask, flag);
  decode_mask_kernel<<<MTOK/256,256,0,stream>>>(mask, flag, validf);
  cast_all_kernel<<<12288,256,0,stream>>>(qkv_w, out_w, w1, w2, wqb, wob, w1b, w2b);

  ln_kernel<<<MTOK,256,0,stream>>>(src, ln1g, ln1b, bufA);
  gemm_bt<0><<<dim3(3072/128, MTOK/128),256,0,stream>>>(bufA, wqb, qkv_b, validf, nullptr, qb, ktb, vtb, MTOK,3072,1024);
  kvz_mfma_kernel<<<2048,64,0,stream>>>(ktb, vtb, kvp, zp);
  kvz_reduce_kernel<<<128,256,0,stream>>>(kvp, zp, kvtb);
  y_gemm_kernel<<<dim3(SEQ/128,128),256,0,stream>>>(qb, kvtb, bufA);
  gemm_bt<1><<<dim3(1024/128, MTOK/128),256,0,stream>>>(bufA, wob, out_b, src, out, nullptr, nullptr, nullptr, MTOK,1024,1024);
  ln_kernel<<<MTOK,256,0,stream>>>(out, ln2g, ln2b, bufA);
  gemm_bt<2><<<dim3(4096/128, MTOK/128),256,0,stream>>>(bufA, w1b, b1, nullptr, nullptr, hbuf, nullptr, nullptr, MTOK,4096,1024);
  gemm_bt<3><<<dim3(1024/128, MTOK/128),256,0,stream>>>(hbuf, w2b, b2, nullptr, out, nullptr, nullptr, nullptr, MTOK,1024,4096);
}